// Round 1
// baseline (7772.539 us; speedup 1.0000x reference)
//
#include <hip/hip_runtime.h>
#include <math.h>

// Problem constants
constexpr int B_  = 64;
constexpr int S_  = 512;
constexpr int H_  = 768;
constexpr int H2_ = 1536;   // 2H
constexpr int G3_ = 2304;   // 3H
constexpr int OP_ = 18;
constexpr int C_  = 24;
constexpr int M_  = 16;
constexpr int E_  = 8;
constexpr int A_  = 3;
constexpr int K_  = 48;     // C+M+E
constexpr int HH_ = 384;    // H/2
constexpr int KH_ = 24;     // K/2

// ---------------------------------------------------------------------------
// Generic tiled f32 GEMM:  C(Mm x Nn) = act( A(Mm x Kk) @ B(Nn x Kk)^T + bias )
// A rows may be gathered via Aidx. Both A and B rows are read contiguously.
// ---------------------------------------------------------------------------
__device__ __forceinline__ void gemm_body(
    const float* __restrict__ A, long lda, const int* __restrict__ Aidx,
    const float* __restrict__ Bw, const float* __restrict__ bias,
    float* __restrict__ Co, int ldc,
    int Mm, int Nn, int Kk, int relu)
{
    __shared__ float As[32][33];
    __shared__ float Bs[32][33];
    const int tid = threadIdx.x;
    const int tx = tid & 15, ty = tid >> 4;
    const int row0 = blockIdx.y << 5, col0 = blockIdx.x << 5;
    float a00 = 0.f, a01 = 0.f, a10 = 0.f, a11 = 0.f;

    for (int k0 = 0; k0 < Kk; k0 += 32) {
        #pragma unroll
        for (int t = tid; t < 1024; t += 256) {
            int r = t >> 5, c = t & 31;
            int gr = row0 + r, gc = k0 + c;
            float va = 0.f;
            if (gr < Mm && gc < Kk) {
                long ar = Aidx ? (long)Aidx[gr] : (long)gr;
                va = A[ar * lda + gc];
            }
            As[r][c] = va;
            int br = col0 + r;
            Bs[r][c] = (br < Nn && gc < Kk) ? Bw[(long)br * Kk + gc] : 0.f;
        }
        __syncthreads();
        #pragma unroll
        for (int kk2 = 0; kk2 < 32; ++kk2) {
            float x0 = As[ty * 2][kk2],     x1 = As[ty * 2 + 1][kk2];
            float y0 = Bs[tx * 2][kk2],     y1 = Bs[tx * 2 + 1][kk2];
            a00 += x0 * y0; a01 += x0 * y1;
            a10 += x1 * y0; a11 += x1 * y1;
        }
        __syncthreads();
    }

    float accs[2][2] = {{a00, a01}, {a10, a11}};
    int r0 = row0 + ty * 2, c0 = col0 + tx * 2;
    #pragma unroll
    for (int dr = 0; dr < 2; ++dr)
        #pragma unroll
        for (int dc = 0; dc < 2; ++dc) {
            int r = r0 + dr, c = c0 + dc;
            if (r < Mm && c < Nn) {
                float v = accs[dr][dc] + (bias ? bias[c] : 0.f);
                if (relu) v = fmaxf(v, 0.f);
                Co[(long)r * ldc + c] = v;
            }
        }
}

__global__ void k_gemm(const float* __restrict__ A, long lda, const int* __restrict__ Aidx,
                       const float* __restrict__ Bw, const float* __restrict__ bias,
                       float* __restrict__ Co, int ldc, int Mm, int Nn, int Kk, int relu)
{
    gemm_body(A, lda, Aidx, Bw, bias, Co, ldc, Mm, Nn, Kk, relu);
}

// Dual GEMM for one GRU layer: z==0 -> gi = x@Wih^T + bih ; z==1 -> gh = h@Whh^T + bhh
__global__ void k_gru_gemm(const float* __restrict__ x, long ldx,
                           const float* __restrict__ h, long ldh,
                           const float* __restrict__ Wih, const float* __restrict__ Whh,
                           const float* __restrict__ bih, const float* __restrict__ bhh,
                           float* __restrict__ gi, float* __restrict__ gh)
{
    if (blockIdx.z == 0)
        gemm_body(x, ldx, nullptr, Wih, bih, gi, G3_, B_, G3_, H_, 0);
    else
        gemm_body(h, ldh, nullptr, Whh, bhh, gh, G3_, B_, G3_, H_, 0);
}

// GRU gate nonlinearity: h_new = (1-z)*n + z*h_prev
__global__ void k_gates(const float* __restrict__ gi, const float* __restrict__ gh,
                        const float* __restrict__ hprev, long ldh, float* __restrict__ hnew)
{
    int idx = blockIdx.x * 256 + threadIdx.x;
    if (idx >= B_ * H_) return;
    int b = idx / H_, j = idx - b * H_;
    const float* gib = gi + (long)b * G3_;
    const float* ghb = gh + (long)b * G3_;
    float ir = gib[j], iz = gib[H_ + j], in_ = gib[2 * H_ + j];
    float hr = ghb[j], hz = ghb[H_ + j], hn  = ghb[2 * H_ + j];
    float r = 1.f / (1.f + expf(-(ir + hr)));
    float z = 1.f / (1.f + expf(-(iz + hz)));
    float n = tanhf(in_ + r * hn);
    float hp = hprev[(long)b * ldh + j];
    hnew[idx] = (1.f - z) * n + z * hp;
}

// Row-wise LayerNorm in place, one block per row of length H_
__global__ void k_ln(float* __restrict__ X, const float* __restrict__ g, const float* __restrict__ be)
{
    long row = blockIdx.x;
    float* xr = X + row * H_;
    int tid = threadIdx.x;
    __shared__ float red[256];

    float s = 0.f;
    for (int h = tid; h < H_; h += 256) s += xr[h];
    red[tid] = s; __syncthreads();
    for (int o = 128; o > 0; o >>= 1) { if (tid < o) red[tid] += red[tid + o]; __syncthreads(); }
    float mu = red[0] / H_;
    __syncthreads();

    float v = 0.f;
    for (int h = tid; h < H_; h += 256) { float d = xr[h] - mu; v += d * d; }
    red[tid] = v; __syncthreads();
    for (int o = 128; o > 0; o >>= 1) { if (tid < o) red[tid] += red[tid + o]; __syncthreads(); }
    float inv = 1.f / sqrtf(red[0] / H_ + 1e-5f);
    __syncthreads();

    for (int h = tid; h < H_; h += 256) xr[h] = (xr[h] - mu) * inv * g[h] + be[h];
}

// Build num_vec: for (b,m) find first/last position with number_mask==m+1
__global__ void k_numvec(const float* __restrict__ inp, const int* __restrict__ nmask,
                         float* __restrict__ numvec)
{
    int b = blockIdx.x / M_, m = blockIdx.x % M_;
    int tid = threadIdx.x;
    int fmin = S_, lmax = -1;
    for (int s = tid; s < S_; s += 256) {
        if (nmask[b * S_ + s] == m + 1) {
            if (s < fmin) fmin = s;
            if (s > lmax) lmax = s;
        }
    }
    __shared__ int sf[256], sl[256];
    sf[tid] = fmin; sl[tid] = lmax; __syncthreads();
    for (int o = 128; o > 0; o >>= 1) {
        if (tid < o) {
            sf[tid] = min(sf[tid], sf[tid + o]);
            sl[tid] = max(sl[tid], sl[tid + o]);
        }
        __syncthreads();
    }
    int first = sf[0], last = sl[0];
    bool exists = (last >= 0);
    if (!exists) { first = 0; last = 0; }
    const float* fv = inp + ((long)b * S_ + first) * H_;
    const float* lv = inp + ((long)b * S_ + last) * H_;
    float* dst = numvec + ((long)b * M_ + m) * H2_;
    for (int h = tid; h < H_; h += 256) {
        dst[h]      = exists ? fv[h] : 0.f;
        dst[H_ + h] = exists ? lv[h] : 0.f;
    }
}

__global__ void k_copy_cv(const float* __restrict__ inp, float* __restrict__ cvv)
{
    int b = blockIdx.x;
    for (int h = threadIdx.x; h < H_; h += 256)
        cvv[b * H_ + h] = inp[(long)b * S_ * H_ + h];
}

// x = _pick(gold_operands[:, i, j-1], pc, pn, prev, bidx)
__global__ void k_pick_x(const int* __restrict__ gopd, int i, int jm1,
                         const float* __restrict__ pcb, const float* __restrict__ pn,
                         const float* __restrict__ prev, float* __restrict__ x)
{
    int b = blockIdx.x;
    int idx = gopd[(b * E_ + i) * A_ + jm1];
    const float* src;
    if (idx < C_)            src = pcb + (long)idx * H_;
    else if (idx < C_ + M_)  src = pn + ((long)b * M_ + (idx - C_)) * H_;
    else                     src = prev + ((long)b * E_ + (idx - C_ - M_)) * H_;
    for (int h = threadIdx.x; h < H_; h += 256) x[b * H_ + h] = src[h];
}

// oidx = argmax(logit); cond update of prev[:, i]; pred = pick(oidx)
__global__ void k_argmax_update(const float* __restrict__ logits, int ldl,
                                float* __restrict__ prev, int i,
                                const float* __restrict__ x,
                                const float* __restrict__ pcb, const float* __restrict__ pn,
                                float* __restrict__ pred)
{
    int b = blockIdx.x, tid = threadIdx.x;
    __shared__ float red[256];
    __shared__ int s_oidx;
    float* prow = prev + ((long)b * E_ + i) * H_;

    // max over prev[b, i, :]  (BEFORE any update this step)
    float m = -3.4e38f;
    for (int h = tid; h < H_; h += 256) m = fmaxf(m, prow[h]);
    red[tid] = m; __syncthreads();
    for (int o = 128; o > 0; o >>= 1) { if (tid < o) red[tid] = fmaxf(red[tid], red[tid + o]); __syncthreads(); }
    float mx = red[0];

    if (tid == 0) {
        // first-max tie semantics (matches jnp.argmax)
        const float* lg = logits + (long)b * ldl;
        float best = lg[0]; int bi = 0;
        for (int k2 = 1; k2 < K_; ++k2) {
            float v = lg[k2];
            if (v > best) { best = v; bi = k2; }
        }
        s_oidx = bi;
    }
    __syncthreads();
    int oidx = s_oidx;
    bool empty = (mx == 0.0f);
    if (oidx == 0 && empty) {                 // (oidx < C) & (oidx == PAD) & empty
        for (int h = tid; h < H_; h += 256) prow[h] = x[b * H_ + h];
    }
    __syncthreads();

    // pred = pick(oidx)  (AFTER the conditional update)
    const float* src;
    if (oidx < C_)            src = pcb + (long)oidx * H_;
    else if (oidx < C_ + M_)  src = pn + ((long)b * M_ + (oidx - C_)) * H_;
    else                      src = prev + ((long)b * E_ + (oidx - C_ - M_)) * H_;
    for (int h = tid; h < H_; h += 256) pred[b * H_ + h] = src[h];
}

__global__ void k_final_update(float* __restrict__ prev, int i, const float* __restrict__ pred)
{
    int b = blockIdx.x, tid = threadIdx.x;
    __shared__ float red[256];
    float* prow = prev + ((long)b * E_ + i) * H_;
    float m = -3.4e38f;
    for (int h = tid; h < H_; h += 256) m = fmaxf(m, prow[h]);
    red[tid] = m; __syncthreads();
    for (int o = 128; o > 0; o >>= 1) { if (tid < o) red[tid] = fmaxf(red[tid], red[tid + o]); __syncthreads(); }
    if (red[0] == 0.0f) {
        for (int h = tid; h < H_; h += 256) prow[h] = pred[b * H_ + h];
    }
}

// ---------------------------------------------------------------------------
extern "C" void kernel_launch(void* const* d_in, const int* in_sizes, int n_in,
                              void* d_out, int out_size, void* d_ws, size_t ws_size,
                              hipStream_t stream)
{
    const float* inp    = (const float*)d_in[0];
    const int*   nmask  = (const int*)  d_in[3];
    const int*   gops   = (const int*)  d_in[4];   // gold_operators (B,E)
    const int*   gopd   = (const int*)  d_in[5];   // gold_operands (B,E,A)
    const float* constv = (const float*)d_in[6];
    const float* opv    = (const float*)d_in[7];
    const float* opj_W  = (const float*)d_in[8];
    const float* opj_b  = (const float*)d_in[9];
    const float* opj_g  = (const float*)d_in[10];
    const float* opj_be = (const float*)d_in[11];
    const float* odj_W  = (const float*)d_in[12];
    const float* odj_b  = (const float*)d_in[13];
    const float* odj_g  = (const float*)d_in[14];
    const float* odj_be = (const float*)d_in[15];
    const float* opc_W1 = (const float*)d_in[16];
    const float* opc_b1 = (const float*)d_in[17];
    const float* opc_W2 = (const float*)d_in[18];
    const float* opc_b2 = (const float*)d_in[19];
    const float* odc_W1 = (const float*)d_in[20];
    const float* odc_b1 = (const float*)d_in[21];
    const float* odc_W2 = (const float*)d_in[22];
    const float* odc_b2 = (const float*)d_in[23];
    const float* og_Wih = (const float*)d_in[24];
    const float* og_Whh = (const float*)d_in[25];
    const float* og_bih = (const float*)d_in[26];
    const float* og_bhh = (const float*)d_in[27];
    const float* cg_Wih = (const float*)d_in[28];
    const float* cg_Whh = (const float*)d_in[29];
    const float* cg_bih = (const float*)d_in[30];
    const float* cg_bhh = (const float*)d_in[31];

    float* op_out = (float*)d_out;                  // (B, E, OP)
    float* od_out = op_out + (long)B_ * E_ * OP_;   // (B, E, A, K)

    // workspace partition (floats)
    float* ws      = (float*)d_ws;
    float* num_vec = ws; ws += (long)B_ * M_ * H2_;
    float* pn      = ws; ws += (long)B_ * M_ * H_;
    float* pcb     = ws; ws += (long)C_ * H_;
    float* gopv    = ws; ws += (long)B_ * E_ * H_;
    float* prev    = ws; ws += (long)B_ * E_ * H_;
    float* cv      = ws; ws += (long)B_ * H_;
    float* h0      = ws; ws += (long)B_ * H_;
    float* hx0     = ws; ws += (long)B_ * H_;
    float* hx1     = ws; ws += (long)B_ * H_;
    float* xbuf    = ws; ws += (long)B_ * H_;
    float* pred    = ws; ws += (long)B_ * H_;
    float* gi      = ws; ws += (long)B_ * G3_;
    float* gh      = ws; ws += (long)B_ * G3_;
    float* hid     = ws; ws += (long)B_ * HH_;

    hipMemsetAsync(prev, 0, (size_t)B_ * E_ * H_ * sizeof(float), stream);

    // ---- preprocessing ----
    k_numvec<<<B_ * M_, 256, 0, stream>>>(inp, nmask, num_vec);

    {   // pn = LN(num_vec @ odj_W^T + odj_b)
        dim3 g((H_ + 31) / 32, (B_ * M_ + 31) / 32);
        k_gemm<<<g, 256, 0, stream>>>(num_vec, H2_, nullptr, odj_W, odj_b, pn, H_, B_ * M_, H_, H2_, 0);
        k_ln<<<B_ * M_, 256, 0, stream>>>(pn, odj_g, odj_be);
    }
    {   // pc = LN(const_vector @ odj_W^T + odj_b)
        dim3 g((H_ + 31) / 32, (C_ + 31) / 32);
        k_gemm<<<g, 256, 0, stream>>>(constv, H2_, nullptr, odj_W, odj_b, pcb, H_, C_, H_, H2_, 0);
        k_ln<<<C_, 256, 0, stream>>>(pcb, odj_g, odj_be);
    }
    {   // gold_opv = LN(operator_vector[gold_operators] @ opj_W^T + opj_b)
        dim3 g((H_ + 31) / 32, (B_ * E_ + 31) / 32);
        k_gemm<<<g, 256, 0, stream>>>(opv, H2_, gops, opj_W, opj_b, gopv, H_, B_ * E_, H_, H2_, 0);
        k_ln<<<B_ * E_, 256, 0, stream>>>(gopv, opj_g, opj_be);
    }
    k_copy_cv<<<B_, 256, 0, stream>>>(inp, cv);

    // ---- decode loop ----
    dim3 gg(G3_ / 32, 2, 2);        // GRU dual-GEMM: 72 x 2 x 2
    dim3 gm1(HH_ / 32, 2);          // op MLP1: N=384
    dim3 gm2(1, 2);                 // op MLP2: N=18
    dim3 gd1(1, 2);                 // od MLP1: N=24
    dim3 gd2((K_ + 31) / 32, 2);    // od MLP2: N=48

    for (int i = 0; i < E_; ++i) {
        if (i > 0) {
            const float* hrow = prev + (long)(i - 1) * H_;   // row stride E_*H_
            k_gru_gemm<<<gg, 256, 0, stream>>>(cv, H_, hrow, (long)E_ * H_,
                                               cg_Wih, cg_Whh, cg_bih, cg_bhh, gi, gh);
            k_gates<<<192, 256, 0, stream>>>(gi, gh, hrow, (long)E_ * H_, h0);
            k_gru_gemm<<<gg, 256, 0, stream>>>(h0, H_, hrow, (long)E_ * H_,
                                               cg_Wih + (long)G3_ * H_, cg_Whh + (long)G3_ * H_,
                                               cg_bih + G3_, cg_bhh + G3_, gi, gh);
            k_gates<<<192, 256, 0, stream>>>(gi, gh, hrow, (long)E_ * H_, cv);
        }
        // op logits
        k_gemm<<<gm1, 256, 0, stream>>>(cv, H_, nullptr, opc_W1, opc_b1, hid, HH_, B_, HH_, H_, 1);
        k_gemm<<<gm2, 256, 0, stream>>>(hid, HH_, nullptr, opc_W2, opc_b2,
                                        op_out + (long)i * OP_, E_ * OP_, B_, OP_, HH_, 0);

        for (int j = 0; j < A_; ++j) {
            const float* xptr; long ldx;
            if (j == 0) { xptr = gopv + (long)i * H_; ldx = (long)E_ * H_; }
            else {
                k_pick_x<<<B_, 256, 0, stream>>>(gopd, i, j - 1, pcb, pn, prev, xbuf);
                xptr = xbuf; ldx = H_;
            }
            const float* hp0 = (j == 0) ? cv : hx0;
            const float* hp1 = (j == 0) ? cv : hx1;

            k_gru_gemm<<<gg, 256, 0, stream>>>(xptr, ldx, hp0, H_,
                                               og_Wih, og_Whh, og_bih, og_bhh, gi, gh);
            k_gates<<<192, 256, 0, stream>>>(gi, gh, hp0, H_, hx0);
            k_gru_gemm<<<gg, 256, 0, stream>>>(hx0, H_, hp1, H_,
                                               og_Wih + (long)G3_ * H_, og_Whh + (long)G3_ * H_,
                                               og_bih + G3_, og_bhh + G3_, gi, gh);
            k_gates<<<192, 256, 0, stream>>>(gi, gh, hp1, H_, hx1);

            // od logits -> d_out directly
            k_gemm<<<gd1, 256, 0, stream>>>(hx1, H_, nullptr, odc_W1, odc_b1, hid, KH_, B_, KH_, H_, 1);
            float* lgptr = od_out + (long)i * A_ * K_ + (long)j * K_;
            k_gemm<<<gd2, 256, 0, stream>>>(hid, KH_, nullptr, odc_W2, odc_b2,
                                            lgptr, E_ * A_ * K_, B_, K_, KH_, 0);

            k_argmax_update<<<B_, 256, 0, stream>>>(lgptr, E_ * A_ * K_, prev, i, hx1, pcb, pn, pred);
        }
        k_final_update<<<B_, 256, 0, stream>>>(prev, i, pred);
    }
}

// Round 2
// 4875.771 us; speedup vs baseline: 1.5941x; 1.5941x over previous
//
#include <hip/hip_runtime.h>
#include <math.h>

// Problem constants
constexpr int B_  = 64;
constexpr int S_  = 512;
constexpr int H_  = 768;
constexpr int H2_ = 1536;   // 2H
constexpr int G3_ = 2304;   // 3H
constexpr int OP_ = 18;
constexpr int C_  = 24;
constexpr int M_  = 16;
constexpr int E_  = 8;
constexpr int A_  = 3;
constexpr int K_  = 48;     // C+M+E
constexpr int HH_ = 384;    // H/2

// ---------------------------------------------------------------------------
// GEMM core: block computes 64 rows x 128 cols of  C = A @ W^T  (partial over
// a K-range), writing raw partials to Pout[r*ldP + c].
// - Acts staged transposed in LDS (As[k][row], stride 68): b128 reads,
//   broadcast across lanes.
// - Weights streamed global->register, prefetched one 4k-chunk ahead.
// - micro-tile: 4 rows x 8 cols per thread, 256 threads (16 rg x 16 cg).
// ---------------------------------------------------------------------------
__device__ __forceinline__ void gemm_core(
    const float* const* rowsrc,          // [64] LDS row pointers (null -> 0)
    const float* __restrict__ W, int wld,
    int col0g,                           // global col of this block's col 0
    int k0base, int nkt,                 // K range [k0base, k0base+nkt*32)
    float* __restrict__ Pout, int ldP)
{
    __shared__ float As[32][68];
    const int tid = threadIdx.x;
    const int cg = tid & 15, rg = tid >> 4;
    const int c0 = cg * 8, r0 = rg * 4;

    float acc[4][8];
    #pragma unroll
    for (int a = 0; a < 4; ++a)
        #pragma unroll
        for (int b = 0; b < 8; ++b) acc[a][b] = 0.f;

    const float* wrow[8];
    #pragma unroll
    for (int j = 0; j < 8; ++j) wrow[j] = W + (long)(col0g + c0 + j) * wld;

    for (int kt = 0; kt < nkt; ++kt) {
        const int k0 = k0base + kt * 32;
        __syncthreads();
        // stage 64x32 acts, transposed
        #pragma unroll
        for (int it = 0; it < 2; ++it) {
            int f = tid + it * 256;          // 512 float4 slots
            int row = f >> 3, f4 = f & 7;
            const float* src = rowsrc[row];
            float4 v = make_float4(0.f, 0.f, 0.f, 0.f);
            if (src) v = *(const float4*)(src + k0 + f4 * 4);
            As[f4 * 4 + 0][row] = v.x;
            As[f4 * 4 + 1][row] = v.y;
            As[f4 * 4 + 2][row] = v.z;
            As[f4 * 4 + 3][row] = v.w;
        }
        __syncthreads();

        float4 wv[8], wn[8];
        #pragma unroll
        for (int j = 0; j < 8; ++j) wv[j] = *(const float4*)(wrow[j] + k0);

        #pragma unroll
        for (int dk = 0; dk < 8; ++dk) {
            if (dk < 7) {
                #pragma unroll
                for (int j = 0; j < 8; ++j)
                    wn[j] = *(const float4*)(wrow[j] + k0 + (dk + 1) * 4);
            }
            #pragma unroll
            for (int dd = 0; dd < 4; ++dd) {
                const int kk = dk * 4 + dd;
                float4 a = *(const float4*)&As[kk][r0];
                float av[4] = {a.x, a.y, a.z, a.w};
                #pragma unroll
                for (int j = 0; j < 8; ++j) {
                    float w = (dd == 0) ? wv[j].x : (dd == 1) ? wv[j].y
                            : (dd == 2) ? wv[j].z : wv[j].w;
                    #pragma unroll
                    for (int rr = 0; rr < 4; ++rr) acc[rr][j] += av[rr] * w;
                }
            }
            #pragma unroll
            for (int j = 0; j < 8; ++j) wv[j] = wn[j];
        }
    }

    #pragma unroll
    for (int rr = 0; rr < 4; ++rr) {
        float4 o0 = make_float4(acc[rr][0], acc[rr][1], acc[rr][2], acc[rr][3]);
        float4 o1 = make_float4(acc[rr][4], acc[rr][5], acc[rr][6], acc[rr][7]);
        float* dst = Pout + (long)(r0 + rr) * ldP + c0;
        *(float4*)dst = o0;
        *(float4*)(dst + 4) = o1;
    }
}

// ---------------------------------------------------------------------------
// GRU dual GEMM: grid (36, 4). bx<18 -> gi cols (x @ Wih^T), else gh cols.
// K=768 split 4 ways (192 each). Optional _pick row-gather on the x side.
// ---------------------------------------------------------------------------
__global__ __launch_bounds__(256) void k_gru_gemm4(
    const float* __restrict__ x, long ldx, int pickmode,
    const int* __restrict__ gopd, int i, int jm1,
    const float* __restrict__ pcb, const float* __restrict__ pnb,
    const float* __restrict__ prevb,
    const float* __restrict__ h, long ldh,
    const float* __restrict__ Wih, const float* __restrict__ Whh,
    float* __restrict__ P)
{
    __shared__ const float* rowsrc[64];
    const int bx = blockIdx.x;
    const int kz = blockIdx.y;
    const bool hside = bx >= 18;
    const int n0 = (bx % 18) * 128;

    if (threadIdx.x < 64) {
        int r = threadIdx.x;
        const float* s;
        if (hside) s = h + (long)r * ldh;
        else if (!pickmode) s = x + (long)r * ldx;
        else {
            int idx = gopd[(r * E_ + i) * A_ + jm1];
            if (idx < C_)            s = pcb + (long)idx * H_;
            else if (idx < C_ + M_)  s = pnb + ((long)r * M_ + (idx - C_)) * H_;
            else                     s = prevb + ((long)r * E_ + (idx - C_ - M_)) * H_;
        }
        rowsrc[r] = s;
    }
    const float* W = hside ? Whh : Wih;
    float* Pout = P + (long)kz * 64 * 4608 + (hside ? 2304 : 0) + n0;
    gemm_core(rowsrc, W, 768, n0, kz * 192, 6, Pout, 4608);
}

// Sum 4 K-partials, add biases, apply GRU gates: hnew = (1-z)*n + z*h
__global__ void k_gru_finish(const float* __restrict__ P,
                             const float* __restrict__ h, long ldh,
                             const float* __restrict__ bih, const float* __restrict__ bhh,
                             float* __restrict__ hnew)
{
    int t = blockIdx.x * 256 + threadIdx.x;       // 64*768
    int b = t / 768, c = t - b * 768;
    const float* Pb = P + (long)b * 4608;
    float ir = bih[c], iz = bih[768 + c], in_ = bih[1536 + c];
    float hr = bhh[c], hz = bhh[768 + c], hn  = bhh[1536 + c];
    #pragma unroll
    for (int z = 0; z < 4; ++z) {
        const float* q = Pb + (long)z * 64 * 4608;
        ir += q[c];        iz += q[768 + c];  in_ += q[1536 + c];
        hr += q[2304 + c]; hz += q[3072 + c]; hn  += q[3840 + c];
    }
    float r  = 1.f / (1.f + expf(-(ir + hr)));
    float z_ = 1.f / (1.f + expf(-(iz + hz)));
    float n  = tanhf(in_ + r * hn);
    float hp = h[(long)b * ldh + c];
    hnew[t] = (1.f - z_) * n + z_ * hp;
}

// ---------------------------------------------------------------------------
// Generic projection GEMM (partials): grid (ncolblk, nrowblk, KS)
// ---------------------------------------------------------------------------
__global__ __launch_bounds__(256) void k_proj_gemm(
    const float* __restrict__ A, long lda, const int* __restrict__ gidx, int Mm,
    const float* __restrict__ W, int wld, int nkt,
    float* __restrict__ P, int ldP, int Mpad)
{
    __shared__ const float* rowsrc[64];
    const int n0 = blockIdx.x * 128;
    const int rb = blockIdx.y * 64;
    const int kz = blockIdx.z;
    if (threadIdx.x < 64) {
        int r = rb + threadIdx.x;
        const float* s = nullptr;
        if (r < Mm) s = gidx ? (A + (long)gidx[r] * lda) : (A + (long)r * lda);
        rowsrc[threadIdx.x] = s;
    }
    float* Pout = P + ((long)kz * Mpad + rb) * ldP + n0;
    gemm_core(rowsrc, W, wld, n0, kz * nkt * 32, nkt, Pout, ldP);
}

// Sum KS partials + bias, then LayerNorm the 768-wide row.
__global__ void k_ln_finish(const float* __restrict__ P, int ldP, int Mpad, int KS,
                            const float* __restrict__ bias, const float* __restrict__ g,
                            const float* __restrict__ be,
                            float* __restrict__ out, long ldout)
{
    int row = blockIdx.x, tid = threadIdx.x;
    __shared__ float red[256];
    float v[3];
    #pragma unroll
    for (int it = 0; it < 3; ++it) {
        int c2 = tid + it * 256;
        float s = bias[c2];
        for (int z = 0; z < KS; ++z) s += P[((long)z * Mpad + row) * ldP + c2];
        v[it] = s;
    }
    float s = v[0] + v[1] + v[2];
    red[tid] = s; __syncthreads();
    for (int o = 128; o > 0; o >>= 1) { if (tid < o) red[tid] += red[tid + o]; __syncthreads(); }
    float mu = red[0] / 768.f;
    __syncthreads();
    float vv = 0.f;
    #pragma unroll
    for (int it = 0; it < 3; ++it) { float d = v[it] - mu; vv += d * d; }
    red[tid] = vv; __syncthreads();
    for (int o = 128; o > 0; o >>= 1) { if (tid < o) red[tid] += red[tid + o]; __syncthreads(); }
    float inv = 1.f / sqrtf(red[0] / 768.f + 1e-5f);
    #pragma unroll
    for (int it = 0; it < 3; ++it) {
        int c2 = tid + it * 256;
        out[(long)row * ldout + c2] = (v[it] - mu) * inv * g[c2] + be[c2];
    }
}

// Sum 4 partials + bias + relu -> hid (64 x 384)
__global__ void k_relu_finish(const float* __restrict__ P,
                              const float* __restrict__ bias, float* __restrict__ out)
{
    int t = blockIdx.x * 256 + threadIdx.x;      // 64*384
    int b = t / 384, c = t - b * 384;
    float s = bias[c];
    #pragma unroll
    for (int z = 0; z < 4; ++z) s += P[((long)z * 64 + b) * 384 + c];
    out[t] = fmaxf(s, 0.f);
}

// op logits: 18 dots of length 384 per batch row
__global__ void k_ophead2(const float* __restrict__ hid, const float* __restrict__ W2,
                          const float* __restrict__ b2, float* __restrict__ op_out, int i)
{
    int b = blockIdx.x, tid = threadIdx.x;
    int c = tid >> 3, g = tid & 7;
    float acc = 0.f;
    if (c < OP_) {
        const float* xr = hid + (long)b * HH_;
        const float* wr = W2 + (long)c * HH_;
        #pragma unroll
        for (int t = 0; t < 12; ++t) {
            int k = (g + 8 * t) * 4;
            float4 xv = *(const float4*)(xr + k);
            float4 wv = *(const float4*)(wr + k);
            acc += xv.x * wv.x + xv.y * wv.y + xv.z * wv.z + xv.w * wv.w;
        }
    }
    acc += __shfl_xor(acc, 1);
    acc += __shfl_xor(acc, 2);
    acc += __shfl_xor(acc, 4);
    if (c < OP_ && g == 0)
        op_out[((long)b * E_ + i) * OP_ + c] = acc + b2[c];
}

// ---------------------------------------------------------------------------
// Fused od head: MLP1(relu) + MLP2 + logit write + argmax + prev update + pred
// one block per batch row
// ---------------------------------------------------------------------------
__global__ __launch_bounds__(256) void k_odhead(
    const float* __restrict__ hx1,
    const float* __restrict__ W1, const float* __restrict__ b1,
    const float* __restrict__ W2, const float* __restrict__ b2,
    float* __restrict__ od_base, long ldl,
    float* __restrict__ prev, int i,
    const float* __restrict__ pcb, const float* __restrict__ pnb,
    float* __restrict__ pred)
{
    int b = blockIdx.x, tid = threadIdx.x;
    __shared__ float xs[768];
    __shared__ float hidL[24];
    __shared__ float lg[48];
    __shared__ float red[256];
    __shared__ int s_oidx;

    const float* xr = hx1 + (long)b * 768;
    #pragma unroll
    for (int it = 0; it < 3; ++it) xs[tid + it * 256] = xr[tid + it * 256];
    __syncthreads();

    int c = tid >> 3, g = tid & 7;
    float acc = 0.f;
    if (c < 24) {
        const float* wr = W1 + (long)c * 768;
        #pragma unroll
        for (int t = 0; t < 24; ++t) {
            int k = (g + 8 * t) * 4;
            float4 xv = *(const float4*)&xs[k];
            float4 wv = *(const float4*)(wr + k);
            acc += xv.x * wv.x + xv.y * wv.y + xv.z * wv.z + xv.w * wv.w;
        }
    }
    acc += __shfl_xor(acc, 1);
    acc += __shfl_xor(acc, 2);
    acc += __shfl_xor(acc, 4);
    if (c < 24 && g == 0) hidL[c] = fmaxf(acc + b1[c], 0.f);
    __syncthreads();

    if (tid < 48) {
        float a2 = b2[tid];
        const float* w2 = W2 + tid * 24;
        #pragma unroll
        for (int k = 0; k < 24; ++k) a2 += hidL[k] * w2[k];
        lg[tid] = a2;
        od_base[(long)b * ldl + tid] = a2;
    }

    // max over prev[b,i,:] BEFORE any update this step
    float* prow = prev + ((long)b * E_ + i) * 768;
    float m = -3.4e38f;
    #pragma unroll
    for (int it = 0; it < 3; ++it) m = fmaxf(m, prow[tid + it * 256]);
    red[tid] = m; __syncthreads();
    for (int o = 128; o > 0; o >>= 1) { if (tid < o) red[tid] = fmaxf(red[tid], red[tid + o]); __syncthreads(); }

    if (tid == 0) {      // first-max tie semantics (matches jnp.argmax)
        float best = lg[0]; int bi = 0;
        for (int k2 = 1; k2 < K_; ++k2) { float v = lg[k2]; if (v > best) { best = v; bi = k2; } }
        s_oidx = bi;
    }
    __syncthreads();
    int oidx = s_oidx;
    bool empty = (red[0] == 0.0f);
    if (oidx == 0 && empty) {     // (oidx < C) & (oidx == PAD) & empty
        #pragma unroll
        for (int it = 0; it < 3; ++it) prow[tid + it * 256] = xs[tid + it * 256];
    }
    __syncthreads();

    const float* src;
    if (oidx < C_)            src = pcb + (long)oidx * 768;
    else if (oidx < C_ + M_)  src = pnb + ((long)b * M_ + (oidx - C_)) * 768;
    else                      src = prev + ((long)b * E_ + (oidx - C_ - M_)) * 768;
    #pragma unroll
    for (int it = 0; it < 3; ++it) pred[(long)b * 768 + tid + it * 256] = src[tid + it * 256];
}

__global__ void k_final_update(float* __restrict__ prev, int i, const float* __restrict__ pred)
{
    int b = blockIdx.x, tid = threadIdx.x;
    __shared__ float red[256];
    float* prow = prev + ((long)b * E_ + i) * H_;
    float m = -3.4e38f;
    #pragma unroll
    for (int it = 0; it < 3; ++it) m = fmaxf(m, prow[tid + it * 256]);
    red[tid] = m; __syncthreads();
    for (int o = 128; o > 0; o >>= 1) { if (tid < o) red[tid] = fmaxf(red[tid], red[tid + o]); __syncthreads(); }
    if (red[0] == 0.0f) {
        #pragma unroll
        for (int it = 0; it < 3; ++it) prow[tid + it * 256] = pred[(long)b * H_ + tid + it * 256];
    }
}

// Build num_vec: for (b,m) find first/last position with number_mask==m+1
__global__ void k_numvec(const float* __restrict__ inp, const int* __restrict__ nmask,
                         float* __restrict__ numvec)
{
    int b = blockIdx.x / M_, m = blockIdx.x % M_;
    int tid = threadIdx.x;
    int fmin = S_, lmax = -1;
    for (int s = tid; s < S_; s += 256) {
        if (nmask[b * S_ + s] == m + 1) {
            if (s < fmin) fmin = s;
            if (s > lmax) lmax = s;
        }
    }
    __shared__ int sf[256], sl[256];
    sf[tid] = fmin; sl[tid] = lmax; __syncthreads();
    for (int o = 128; o > 0; o >>= 1) {
        if (tid < o) {
            sf[tid] = min(sf[tid], sf[tid + o]);
            sl[tid] = max(sl[tid], sl[tid + o]);
        }
        __syncthreads();
    }
    int first = sf[0], last = sl[0];
    bool exists = (last >= 0);
    if (!exists) { first = 0; last = 0; }
    const float* fv = inp + ((long)b * S_ + first) * H_;
    const float* lv = inp + ((long)b * S_ + last) * H_;
    float* dst = numvec + ((long)b * M_ + m) * H2_;
    for (int h = tid; h < H_; h += 256) {
        dst[h]      = exists ? fv[h] : 0.f;
        dst[H_ + h] = exists ? lv[h] : 0.f;
    }
}

__global__ void k_copy_cv(const float* __restrict__ inp, float* __restrict__ cvv)
{
    int b = blockIdx.x;
    for (int h = threadIdx.x; h < H_; h += 256)
        cvv[b * H_ + h] = inp[(long)b * S_ * H_ + h];
}

// ---------------------------------------------------------------------------
extern "C" void kernel_launch(void* const* d_in, const int* in_sizes, int n_in,
                              void* d_out, int out_size, void* d_ws, size_t ws_size,
                              hipStream_t stream)
{
    const float* inp    = (const float*)d_in[0];
    const int*   nmask  = (const int*)  d_in[3];
    const int*   gops   = (const int*)  d_in[4];
    const int*   gopd   = (const int*)  d_in[5];
    const float* constv = (const float*)d_in[6];
    const float* opv    = (const float*)d_in[7];
    const float* opj_W  = (const float*)d_in[8];
    const float* opj_b  = (const float*)d_in[9];
    const float* opj_g  = (const float*)d_in[10];
    const float* opj_be = (const float*)d_in[11];
    const float* odj_W  = (const float*)d_in[12];
    const float* odj_b  = (const float*)d_in[13];
    const float* odj_g  = (const float*)d_in[14];
    const float* odj_be = (const float*)d_in[15];
    const float* opc_W1 = (const float*)d_in[16];
    const float* opc_b1 = (const float*)d_in[17];
    const float* opc_W2 = (const float*)d_in[18];
    const float* opc_b2 = (const float*)d_in[19];
    const float* odc_W1 = (const float*)d_in[20];
    const float* odc_b1 = (const float*)d_in[21];
    const float* odc_W2 = (const float*)d_in[22];
    const float* odc_b2 = (const float*)d_in[23];
    const float* og_Wih = (const float*)d_in[24];
    const float* og_Whh = (const float*)d_in[25];
    const float* og_bih = (const float*)d_in[26];
    const float* og_bhh = (const float*)d_in[27];
    const float* cg_Wih = (const float*)d_in[28];
    const float* cg_Whh = (const float*)d_in[29];
    const float* cg_bih = (const float*)d_in[30];
    const float* cg_bhh = (const float*)d_in[31];

    float* op_out = (float*)d_out;                  // (B, E, OP)
    float* od_out = op_out + (long)B_ * E_ * OP_;   // (B, E, A, K)

    // workspace partition (floats)  total ~19.1 MB
    float* ws      = (float*)d_ws;
    float* num_vec = ws; ws += (long)B_ * M_ * H2_;       // 1.57M
    float* P       = ws; ws += (long)2 * 1024 * 768;      // 1.57M (shared partials)
    float* pn      = ws; ws += (long)B_ * M_ * H_;
    float* pcb     = ws; ws += (long)C_ * H_;
    float* gopv    = ws; ws += (long)B_ * E_ * H_;
    float* prev    = ws; ws += (long)B_ * E_ * H_;
    float* cv      = ws; ws += (long)B_ * H_;
    float* h0      = ws; ws += (long)B_ * H_;
    float* hx0     = ws; ws += (long)B_ * H_;
    float* hx1     = ws; ws += (long)B_ * H_;
    float* pred    = ws; ws += (long)B_ * H_;
    float* hid     = ws; ws += (long)B_ * HH_;

    hipMemsetAsync(prev, 0, (size_t)B_ * E_ * H_ * sizeof(float), stream);

    // ---- preprocessing ----
    k_numvec<<<B_ * M_, 256, 0, stream>>>(inp, nmask, num_vec);

    // pn = LN(num_vec @ odj_W^T + odj_b)   M=1024, N=768, K=1536, KS=2
    k_proj_gemm<<<dim3(6, 16, 2), 256, 0, stream>>>(num_vec, H2_, nullptr, 1024,
                                                    odj_W, H2_, 24, P, H_, 1024);
    k_ln_finish<<<1024, 256, 0, stream>>>(P, H_, 1024, 2, odj_b, odj_g, odj_be, pn, H_);

    // pc = LN(const_vector @ odj_W^T + odj_b)   M=24 (padded to 64)
    k_proj_gemm<<<dim3(6, 1, 2), 256, 0, stream>>>(constv, H2_, nullptr, C_,
                                                   odj_W, H2_, 24, P, H_, 64);
    k_ln_finish<<<C_, 256, 0, stream>>>(P, H_, 64, 2, odj_b, odj_g, odj_be, pcb, H_);

    // gold_opv = LN(operator_vector[gold_operators] @ opj_W^T + opj_b)  M=512
    k_proj_gemm<<<dim3(6, 8, 2), 256, 0, stream>>>(opv, H2_, gops, 512,
                                                   opj_W, H2_, 24, P, H_, 512);
    k_ln_finish<<<512, 256, 0, stream>>>(P, H_, 512, 2, opj_b, opj_g, opj_be, gopv, H_);

    k_copy_cv<<<B_, 256, 0, stream>>>(inp, cv);

    // ---- decode loop ----
    const dim3 gg(36, 4);       // GRU GEMM: 144 blocks
    const long ldE = (long)E_ * H_;

    for (int i = 0; i < E_; ++i) {
        if (i > 0) {
            const float* hrow = prev + (long)(i - 1) * H_;   // row stride E*H
            // cg layer 0: x=cv, h=hrow -> h0
            k_gru_gemm4<<<gg, 256, 0, stream>>>(cv, H_, 0, nullptr, 0, 0, nullptr, nullptr, nullptr,
                                                hrow, ldE, cg_Wih, cg_Whh, P);
            k_gru_finish<<<192, 256, 0, stream>>>(P, hrow, ldE, cg_bih, cg_bhh, h0);
            // cg layer 1: x=h0, h=hrow -> cv
            k_gru_gemm4<<<gg, 256, 0, stream>>>(h0, H_, 0, nullptr, 0, 0, nullptr, nullptr, nullptr,
                                                hrow, ldE, cg_Wih + (long)G3_ * H_,
                                                cg_Whh + (long)G3_ * H_, P);
            k_gru_finish<<<192, 256, 0, stream>>>(P, hrow, ldE, cg_bih + G3_, cg_bhh + G3_, cv);
        }
        // op head: hid = relu(cv@W1^T+b1); logits = hid@W2^T+b2
        k_proj_gemm<<<dim3(3, 1, 4), 256, 0, stream>>>(cv, H_, nullptr, B_,
                                                       opc_W1, H_, 6, P, HH_, 64);
        k_relu_finish<<<96, 256, 0, stream>>>(P, opc_b1, hid);
        k_ophead2<<<B_, 256, 0, stream>>>(hid, opc_W2, opc_b2, op_out, i);

        for (int j = 0; j < A_; ++j) {
            const float* xptr; long ldx; int pickm;
            if (j == 0) { xptr = gopv + (long)i * H_; ldx = ldE; pickm = 0; }
            else        { xptr = nullptr; ldx = 0; pickm = 1; }
            const float* hp0 = (j == 0) ? cv : hx0;
            const float* hp1 = (j == 0) ? cv : hx1;

            // og layer 0: x (maybe gathered), h=hp0 -> hx0
            k_gru_gemm4<<<gg, 256, 0, stream>>>(xptr, ldx, pickm, gopd, i, j - 1,
                                                pcb, pn, prev, hp0, H_,
                                                og_Wih, og_Whh, P);
            k_gru_finish<<<192, 256, 0, stream>>>(P, hp0, H_, og_bih, og_bhh, hx0);
            // og layer 1: x=hx0, h=hp1 -> hx1
            k_gru_gemm4<<<gg, 256, 0, stream>>>(hx0, H_, 0, nullptr, 0, 0, nullptr, nullptr, nullptr,
                                                hp1, H_, og_Wih + (long)G3_ * H_,
                                                og_Whh + (long)G3_ * H_, P);
            k_gru_finish<<<192, 256, 0, stream>>>(P, hp1, H_, og_bih + G3_, og_bhh + G3_, hx1);

            // fused od head
            float* od_base = od_out + ((long)i * A_ + j) * K_;
            k_odhead<<<B_, 256, 0, stream>>>(hx1, odc_W1, odc_b1, odc_W2, odc_b2,
                                             od_base, (long)E_ * A_ * K_,
                                             prev, i, pcb, pn, pred);
        }
        k_final_update<<<B_, 256, 0, stream>>>(prev, i, pred);
    }
}

// Round 3
// 3569.132 us; speedup vs baseline: 2.1777x; 1.3661x over previous
//
#include <hip/hip_runtime.h>
#include <math.h>

// Problem constants
constexpr int B_  = 64;
constexpr int S_  = 512;
constexpr int H_  = 768;
constexpr int H2_ = 1536;   // 2H
constexpr int G3_ = 2304;   // 3H
constexpr int OP_ = 18;
constexpr int C_  = 24;
constexpr int M_  = 16;
constexpr int E_  = 8;
constexpr int A_  = 3;
constexpr int K_  = 48;     // C+M+E
constexpr int HH_ = 384;    // H/2

// ---------------------------------------------------------------------------
// GEMM core: block computes 64 rows x 64 cols of  C = A @ W^T  (partial over
// a K-range), writing raw partials to Pout[r*ldP + c].
// - Acts staged transposed in LDS (As[k][row], stride 68 -> aligned b128).
// - Weights streamed global->register, prefetched one 4k-chunk ahead.
// - micro-tile: 4 rows x 4 cols per thread, 256 threads.
// ---------------------------------------------------------------------------
__device__ __forceinline__ void gemm_core64(
    const float* const* rowsrc,          // [64] row pointers (null -> 0)
    const float* __restrict__ W, int wld,
    int col0g,                           // global col of this block's col 0
    int k0base, int nkt,                 // K range [k0base, k0base+nkt*32)
    float* __restrict__ Pout, int ldP)
{
    __shared__ float As[32][68];
    const int tid = threadIdx.x;
    const int cg = tid & 15, rg = tid >> 4;
    const int c0 = cg * 4, r0 = rg * 4;

    float acc[4][4];
    #pragma unroll
    for (int a = 0; a < 4; ++a)
        #pragma unroll
        for (int b = 0; b < 4; ++b) acc[a][b] = 0.f;

    const float* wrow[4];
    #pragma unroll
    for (int j = 0; j < 4; ++j) wrow[j] = W + (long)(col0g + c0 + j) * wld;

    for (int kt = 0; kt < nkt; ++kt) {
        const int k0 = k0base + kt * 32;
        __syncthreads();
        // stage 64x32 acts, transposed
        #pragma unroll
        for (int it = 0; it < 2; ++it) {
            int f = tid + it * 256;          // 512 float4 slots
            int row = f >> 3, f4 = f & 7;
            const float* src = rowsrc[row];
            float4 v = make_float4(0.f, 0.f, 0.f, 0.f);
            if (src) v = *(const float4*)(src + k0 + f4 * 4);
            As[f4 * 4 + 0][row] = v.x;
            As[f4 * 4 + 1][row] = v.y;
            As[f4 * 4 + 2][row] = v.z;
            As[f4 * 4 + 3][row] = v.w;
        }
        __syncthreads();

        float4 wv[4], wn[4];
        #pragma unroll
        for (int j = 0; j < 4; ++j) wv[j] = *(const float4*)(wrow[j] + k0);

        #pragma unroll
        for (int dk = 0; dk < 8; ++dk) {
            if (dk < 7) {
                #pragma unroll
                for (int j = 0; j < 4; ++j)
                    wn[j] = *(const float4*)(wrow[j] + k0 + (dk + 1) * 4);
            }
            #pragma unroll
            for (int dd = 0; dd < 4; ++dd) {
                const int kk = dk * 4 + dd;
                float4 a = *(const float4*)&As[kk][r0];
                float av[4] = {a.x, a.y, a.z, a.w};
                #pragma unroll
                for (int j = 0; j < 4; ++j) {
                    float w = (dd == 0) ? wv[j].x : (dd == 1) ? wv[j].y
                            : (dd == 2) ? wv[j].z : wv[j].w;
                    #pragma unroll
                    for (int rr = 0; rr < 4; ++rr) acc[rr][j] += av[rr] * w;
                }
            }
            #pragma unroll
            for (int j = 0; j < 4; ++j) wv[j] = wn[j];
        }
    }

    #pragma unroll
    for (int rr = 0; rr < 4; ++rr) {
        float4 o = make_float4(acc[rr][0], acc[rr][1], acc[rr][2], acc[rr][3]);
        *(float4*)(Pout + (long)(r0 + rr) * ldP + c0) = o;
    }
}

// ---------------------------------------------------------------------------
// GRU dual GEMM: grid (72, 8). bx<36 -> gi cols (x @ Wih^T), else gh cols.
// K=768 split 8 ways (96 each). Optional _pick row-gather on the x side.
// ---------------------------------------------------------------------------
__global__ __launch_bounds__(256) void k_gru_gemm8(
    const float* __restrict__ x, long ldx, int pickmode,
    const int* __restrict__ gopd, int i, int jm1,
    const float* __restrict__ pcb, const float* __restrict__ pnb,
    const float* __restrict__ prevb,
    const float* __restrict__ h, long ldh,
    const float* __restrict__ Wih, const float* __restrict__ Whh,
    float* __restrict__ P)
{
    __shared__ const float* rowsrc[64];
    const int bx = blockIdx.x;
    const int kz = blockIdx.y;
    const bool hside = bx >= 36;
    const int n0 = (bx % 36) * 64;

    if (threadIdx.x < 64) {
        int r = threadIdx.x;
        const float* s;
        if (hside) s = h + (long)r * ldh;
        else if (!pickmode) s = x + (long)r * ldx;
        else {
            int idx = gopd[(r * E_ + i) * A_ + jm1];
            if (idx < C_)            s = pcb + (long)idx * H_;
            else if (idx < C_ + M_)  s = pnb + ((long)r * M_ + (idx - C_)) * H_;
            else                     s = prevb + ((long)r * E_ + (idx - C_ - M_)) * H_;
        }
        rowsrc[r] = s;
    }
    const float* W = hside ? Whh : Wih;
    float* Pout = P + (long)kz * 64 * 4608 + (hside ? 2304 : 0) + n0;
    gemm_core64(rowsrc, W, 768, n0, kz * 96, 3, Pout, 4608);
}

// Sum 8 K-partials, add biases, apply GRU gates: hnew = (1-z)*n + z*h
__global__ void k_gru_finish8(const float* __restrict__ P,
                              const float* __restrict__ h, long ldh,
                              const float* __restrict__ bih, const float* __restrict__ bhh,
                              float* __restrict__ hnew)
{
    int t = blockIdx.x * 256 + threadIdx.x;       // 64*768
    int b = t / 768, c = t - b * 768;
    const float* Pb = P + (long)b * 4608;
    float ir = bih[c], iz = bih[768 + c], in_ = bih[1536 + c];
    float hr = bhh[c], hz = bhh[768 + c], hn  = bhh[1536 + c];
    #pragma unroll
    for (int z = 0; z < 8; ++z) {
        const float* q = Pb + (long)z * 64 * 4608;
        ir += q[c];        iz += q[768 + c];  in_ += q[1536 + c];
        hr += q[2304 + c]; hz += q[3072 + c]; hn  += q[3840 + c];
    }
    float r  = 1.f / (1.f + expf(-(ir + hr)));
    float z_ = 1.f / (1.f + expf(-(iz + hz)));
    float n  = tanhf(in_ + r * hn);
    float hp = h[(long)b * ldh + c];
    hnew[t] = (1.f - z_) * n + z_ * hp;
}

// ---------------------------------------------------------------------------
// Generic projection GEMM (partials): grid (ncolblk64, nrowblk, KS)
// ---------------------------------------------------------------------------
__global__ __launch_bounds__(256) void k_proj_gemm(
    const float* __restrict__ A, long lda, const int* __restrict__ gidx, int Mm,
    const float* __restrict__ W, int wld, int nkt,
    float* __restrict__ P, int ldP, int Mpad)
{
    __shared__ const float* rowsrc[64];
    const int n0 = blockIdx.x * 64;
    const int rb = blockIdx.y * 64;
    const int kz = blockIdx.z;
    if (threadIdx.x < 64) {
        int r = rb + threadIdx.x;
        const float* s = nullptr;
        if (r < Mm) s = gidx ? (A + (long)gidx[r] * lda) : (A + (long)r * lda);
        rowsrc[threadIdx.x] = s;
    }
    float* Pout = P + ((long)kz * Mpad + rb) * ldP + n0;
    gemm_core64(rowsrc, W, wld, n0, kz * nkt * 32, nkt, Pout, ldP);
}

// Sum KS=4 partials + bias, then LayerNorm the 768-wide row.
__global__ void k_ln_finish(const float* __restrict__ P, int ldP, int Mpad,
                            const float* __restrict__ bias, const float* __restrict__ g,
                            const float* __restrict__ be,
                            float* __restrict__ out, long ldout)
{
    int row = blockIdx.x, tid = threadIdx.x;
    __shared__ float red[256];
    float v[3];
    #pragma unroll
    for (int it = 0; it < 3; ++it) {
        int c2 = tid + it * 256;
        float s = bias[c2];
        #pragma unroll
        for (int z = 0; z < 4; ++z) s += P[((long)z * Mpad + row) * ldP + c2];
        v[it] = s;
    }
    float s = v[0] + v[1] + v[2];
    red[tid] = s; __syncthreads();
    for (int o = 128; o > 0; o >>= 1) { if (tid < o) red[tid] += red[tid + o]; __syncthreads(); }
    float mu = red[0] / 768.f;
    __syncthreads();
    float vv = 0.f;
    #pragma unroll
    for (int it = 0; it < 3; ++it) { float d = v[it] - mu; vv += d * d; }
    red[tid] = vv; __syncthreads();
    for (int o = 128; o > 0; o >>= 1) { if (tid < o) red[tid] += red[tid + o]; __syncthreads(); }
    float inv = 1.f / sqrtf(red[0] / 768.f + 1e-5f);
    #pragma unroll
    for (int it = 0; it < 3; ++it) {
        int c2 = tid + it * 256;
        out[(long)row * ldout + c2] = (v[it] - mu) * inv * g[c2] + be[c2];
    }
}

// Fused op head: hid = relu(cv@W1^T+b1) (384), logits = hid@W2^T+b2 (18)
__global__ __launch_bounds__(256) void k_ophead_fused(
    const float* __restrict__ cv,
    const float* __restrict__ W1, const float* __restrict__ b1,
    const float* __restrict__ W2, const float* __restrict__ b2,
    float* __restrict__ op_out, int i)
{
    int b = blockIdx.x, tid = threadIdx.x;
    __shared__ float xs[768];
    __shared__ float hs[384];
    const float* xr = cv + (long)b * 768;
    #pragma unroll
    for (int it = 0; it < 3; ++it) xs[tid + it * 256] = xr[tid + it * 256];
    __syncthreads();

    for (int c = tid; c < 384; c += 256) {
        const float* wr = W1 + (long)c * 768;
        float acc = 0.f;
        #pragma unroll 8
        for (int k = 0; k < 768; k += 4) {
            float4 xv = *(const float4*)&xs[k];
            float4 wv = *(const float4*)(wr + k);
            acc += xv.x * wv.x + xv.y * wv.y + xv.z * wv.z + xv.w * wv.w;
        }
        hs[c] = fmaxf(acc + b1[c], 0.f);
    }
    __syncthreads();

    int c = tid >> 3, g = tid & 7;
    float acc = 0.f;
    if (c < OP_) {
        const float* wr = W2 + (long)c * HH_;
        #pragma unroll
        for (int t = 0; t < 12; ++t) {
            int k = (g + 8 * t) * 4;
            float4 xv = *(const float4*)&hs[k];
            float4 wv = *(const float4*)(wr + k);
            acc += xv.x * wv.x + xv.y * wv.y + xv.z * wv.z + xv.w * wv.w;
        }
    }
    acc += __shfl_xor(acc, 1);
    acc += __shfl_xor(acc, 2);
    acc += __shfl_xor(acc, 4);
    if (c < OP_ && g == 0)
        op_out[((long)b * E_ + i) * OP_ + c] = acc + b2[c];
}

// ---------------------------------------------------------------------------
// Fused od head: MLP1(relu) + MLP2 + logit write + argmax + prev update + pred
// ---------------------------------------------------------------------------
__global__ __launch_bounds__(256) void k_odhead(
    const float* __restrict__ hx1,
    const float* __restrict__ W1, const float* __restrict__ b1,
    const float* __restrict__ W2, const float* __restrict__ b2,
    float* __restrict__ od_base, long ldl,
    float* __restrict__ prev, int i,
    const float* __restrict__ pcb, const float* __restrict__ pnb,
    float* __restrict__ pred)
{
    int b = blockIdx.x, tid = threadIdx.x;
    __shared__ float xs[768];
    __shared__ float hidL[24];
    __shared__ float lg[48];
    __shared__ float red[256];
    __shared__ int s_oidx;

    const float* xr = hx1 + (long)b * 768;
    #pragma unroll
    for (int it = 0; it < 3; ++it) xs[tid + it * 256] = xr[tid + it * 256];
    __syncthreads();

    int c = tid >> 3, g = tid & 7;
    float acc = 0.f;
    if (c < 24) {
        const float* wr = W1 + (long)c * 768;
        #pragma unroll
        for (int t = 0; t < 24; ++t) {
            int k = (g + 8 * t) * 4;
            float4 xv = *(const float4*)&xs[k];
            float4 wv = *(const float4*)(wr + k);
            acc += xv.x * wv.x + xv.y * wv.y + xv.z * wv.z + xv.w * wv.w;
        }
    }
    acc += __shfl_xor(acc, 1);
    acc += __shfl_xor(acc, 2);
    acc += __shfl_xor(acc, 4);
    if (c < 24 && g == 0) hidL[c] = fmaxf(acc + b1[c], 0.f);
    __syncthreads();

    if (tid < 48) {
        float a2 = b2[tid];
        const float* w2 = W2 + tid * 24;
        #pragma unroll
        for (int k = 0; k < 24; ++k) a2 += hidL[k] * w2[k];
        lg[tid] = a2;
        od_base[(long)b * ldl + tid] = a2;
    }

    float* prow = prev + ((long)b * E_ + i) * 768;
    float m = -3.4e38f;
    #pragma unroll
    for (int it = 0; it < 3; ++it) m = fmaxf(m, prow[tid + it * 256]);
    red[tid] = m; __syncthreads();
    for (int o = 128; o > 0; o >>= 1) { if (tid < o) red[tid] = fmaxf(red[tid], red[tid + o]); __syncthreads(); }

    if (tid == 0) {
        float best = lg[0]; int bi = 0;
        for (int k2 = 1; k2 < K_; ++k2) { float v = lg[k2]; if (v > best) { best = v; bi = k2; } }
        s_oidx = bi;
    }
    __syncthreads();
    int oidx = s_oidx;
    bool empty = (red[0] == 0.0f);
    if (oidx == 0 && empty) {
        #pragma unroll
        for (int it = 0; it < 3; ++it) prow[tid + it * 256] = xs[tid + it * 256];
    }
    __syncthreads();

    const float* src;
    if (oidx < C_)            src = pcb + (long)oidx * 768;
    else if (oidx < C_ + M_)  src = pnb + ((long)b * M_ + (oidx - C_)) * 768;
    else                      src = prev + ((long)b * E_ + (oidx - C_ - M_)) * 768;
    #pragma unroll
    for (int it = 0; it < 3; ++it) pred[(long)b * 768 + tid + it * 256] = src[tid + it * 256];
}

__global__ void k_final_update(float* __restrict__ prev, int i, const float* __restrict__ pred)
{
    int b = blockIdx.x, tid = threadIdx.x;
    __shared__ float red[256];
    float* prow = prev + ((long)b * E_ + i) * H_;
    float m = -3.4e38f;
    #pragma unroll
    for (int it = 0; it < 3; ++it) m = fmaxf(m, prow[tid + it * 256]);
    red[tid] = m; __syncthreads();
    for (int o = 128; o > 0; o >>= 1) { if (tid < o) red[tid] = fmaxf(red[tid], red[tid + o]); __syncthreads(); }
    if (red[0] == 0.0f) {
        #pragma unroll
        for (int it = 0; it < 3; ++it) prow[tid + it * 256] = pred[(long)b * H_ + tid + it * 256];
    }
}

// Build num_vec: for (b,m) find first/last position with number_mask==m+1
__global__ void k_numvec(const float* __restrict__ inp, const int* __restrict__ nmask,
                         float* __restrict__ numvec)
{
    int b = blockIdx.x / M_, m = blockIdx.x % M_;
    int tid = threadIdx.x;
    int fmin = S_, lmax = -1;
    for (int s = tid; s < S_; s += 256) {
        if (nmask[b * S_ + s] == m + 1) {
            if (s < fmin) fmin = s;
            if (s > lmax) lmax = s;
        }
    }
    __shared__ int sf[256], sl[256];
    sf[tid] = fmin; sl[tid] = lmax; __syncthreads();
    for (int o = 128; o > 0; o >>= 1) {
        if (tid < o) {
            sf[tid] = min(sf[tid], sf[tid + o]);
            sl[tid] = max(sl[tid], sl[tid + o]);
        }
        __syncthreads();
    }
    int first = sf[0], last = sl[0];
    bool exists = (last >= 0);
    if (!exists) { first = 0; last = 0; }
    const float* fv = inp + ((long)b * S_ + first) * H_;
    const float* lv = inp + ((long)b * S_ + last) * H_;
    float* dst = numvec + ((long)b * M_ + m) * H2_;
    for (int h = tid; h < H_; h += 256) {
        dst[h]      = exists ? fv[h] : 0.f;
        dst[H_ + h] = exists ? lv[h] : 0.f;
    }
}

__global__ void k_copy_cv(const float* __restrict__ inp, float* __restrict__ cvv)
{
    int b = blockIdx.x;
    for (int h = threadIdx.x; h < H_; h += 256)
        cvv[b * H_ + h] = inp[(long)b * S_ * H_ + h];
}

// ---------------------------------------------------------------------------
extern "C" void kernel_launch(void* const* d_in, const int* in_sizes, int n_in,
                              void* d_out, int out_size, void* d_ws, size_t ws_size,
                              hipStream_t stream)
{
    const float* inp    = (const float*)d_in[0];
    const int*   nmask  = (const int*)  d_in[3];
    const int*   gops   = (const int*)  d_in[4];
    const int*   gopd   = (const int*)  d_in[5];
    const float* constv = (const float*)d_in[6];
    const float* opv    = (const float*)d_in[7];
    const float* opj_W  = (const float*)d_in[8];
    const float* opj_b  = (const float*)d_in[9];
    const float* opj_g  = (const float*)d_in[10];
    const float* opj_be = (const float*)d_in[11];
    const float* odj_W  = (const float*)d_in[12];
    const float* odj_b  = (const float*)d_in[13];
    const float* odj_g  = (const float*)d_in[14];
    const float* odj_be = (const float*)d_in[15];
    const float* opc_W1 = (const float*)d_in[16];
    const float* opc_b1 = (const float*)d_in[17];
    const float* opc_W2 = (const float*)d_in[18];
    const float* opc_b2 = (const float*)d_in[19];
    const float* odc_W1 = (const float*)d_in[20];
    const float* odc_b1 = (const float*)d_in[21];
    const float* odc_W2 = (const float*)d_in[22];
    const float* odc_b2 = (const float*)d_in[23];
    const float* og_Wih = (const float*)d_in[24];
    const float* og_Whh = (const float*)d_in[25];
    const float* og_bih = (const float*)d_in[26];
    const float* og_bhh = (const float*)d_in[27];
    const float* cg_Wih = (const float*)d_in[28];
    const float* cg_Whh = (const float*)d_in[29];
    const float* cg_bih = (const float*)d_in[30];
    const float* cg_bhh = (const float*)d_in[31];

    float* op_out = (float*)d_out;                  // (B, E, OP)
    float* od_out = op_out + (long)B_ * E_ * OP_;   // (B, E, A, K)

    // workspace partition (floats)
    float* ws      = (float*)d_ws;
    float* num_vec = ws; ws += (long)B_ * M_ * H2_;       // 1.57M
    float* P       = ws; ws += (long)4 * 1024 * 768;      // 3.15M partials
    float* pn      = ws; ws += (long)B_ * M_ * H_;
    float* pcb     = ws; ws += (long)C_ * H_;
    float* gopv    = ws; ws += (long)B_ * E_ * H_;
    float* prev    = ws; ws += (long)B_ * E_ * H_;
    float* cv      = ws; ws += (long)B_ * H_;
    float* h0      = ws; ws += (long)B_ * H_;
    float* hx0     = ws; ws += (long)B_ * H_;
    float* hx1     = ws; ws += (long)B_ * H_;
    float* pred    = ws; ws += (long)B_ * H_;

    hipMemsetAsync(prev, 0, (size_t)B_ * E_ * H_ * sizeof(float), stream);

    // ---- preprocessing ----
    k_numvec<<<B_ * M_, 256, 0, stream>>>(inp, nmask, num_vec);

    // pn = LN(num_vec @ odj_W^T + odj_b)   M=1024, N=768, K=1536, KS=4
    k_proj_gemm<<<dim3(12, 16, 4), 256, 0, stream>>>(num_vec, H2_, nullptr, 1024,
                                                     odj_W, H2_, 12, P, H_, 1024);
    k_ln_finish<<<1024, 256, 0, stream>>>(P, H_, 1024, odj_b, odj_g, odj_be, pn, H_);

    // pc = LN(const_vector @ odj_W^T + odj_b)   M=24 (padded to 64)
    k_proj_gemm<<<dim3(12, 1, 4), 256, 0, stream>>>(constv, H2_, nullptr, C_,
                                                    odj_W, H2_, 12, P, H_, 64);
    k_ln_finish<<<C_, 256, 0, stream>>>(P, H_, 64, odj_b, odj_g, odj_be, pcb, H_);

    // gold_opv = LN(operator_vector[gold_operators] @ opj_W^T + opj_b)  M=512
    k_proj_gemm<<<dim3(12, 8, 4), 256, 0, stream>>>(opv, H2_, gops, 512,
                                                    opj_W, H2_, 12, P, H_, 512);
    k_ln_finish<<<512, 256, 0, stream>>>(P, H_, 512, opj_b, opj_g, opj_be, gopv, H_);

    k_copy_cv<<<B_, 256, 0, stream>>>(inp, cv);

    // ---- decode loop ----
    const dim3 gg(72, 8);       // GRU GEMM: 576 blocks
    const long ldE = (long)E_ * H_;

    for (int i = 0; i < E_; ++i) {
        if (i > 0) {
            const float* hrow = prev + (long)(i - 1) * H_;   // row stride E*H
            k_gru_gemm8<<<gg, 256, 0, stream>>>(cv, H_, 0, nullptr, 0, 0, nullptr, nullptr, nullptr,
                                                hrow, ldE, cg_Wih, cg_Whh, P);
            k_gru_finish8<<<192, 256, 0, stream>>>(P, hrow, ldE, cg_bih, cg_bhh, h0);
            k_gru_gemm8<<<gg, 256, 0, stream>>>(h0, H_, 0, nullptr, 0, 0, nullptr, nullptr, nullptr,
                                                hrow, ldE, cg_Wih + (long)G3_ * H_,
                                                cg_Whh + (long)G3_ * H_, P);
            k_gru_finish8<<<192, 256, 0, stream>>>(P, hrow, ldE, cg_bih + G3_, cg_bhh + G3_, cv);
        }
        // op head (fully fused)
        k_ophead_fused<<<B_, 256, 0, stream>>>(cv, opc_W1, opc_b1, opc_W2, opc_b2, op_out, i);

        for (int j = 0; j < A_; ++j) {
            const float* xptr; long ldx; int pickm;
            if (j == 0) { xptr = gopv + (long)i * H_; ldx = ldE; pickm = 0; }
            else        { xptr = nullptr; ldx = 0; pickm = 1; }
            const float* hp0 = (j == 0) ? cv : hx0;
            const float* hp1 = (j == 0) ? cv : hx1;

            k_gru_gemm8<<<gg, 256, 0, stream>>>(xptr, ldx, pickm, gopd, i, j - 1,
                                                pcb, pn, prev, hp0, H_,
                                                og_Wih, og_Whh, P);
            k_gru_finish8<<<192, 256, 0, stream>>>(P, hp0, H_, og_bih, og_bhh, hx0);
            k_gru_gemm8<<<gg, 256, 0, stream>>>(hx0, H_, 0, nullptr, 0, 0, nullptr, nullptr, nullptr,
                                                hp1, H_, og_Wih + (long)G3_ * H_,
                                                og_Whh + (long)G3_ * H_, P);
            k_gru_finish8<<<192, 256, 0, stream>>>(P, hp1, H_, og_bih + G3_, og_bhh + G3_, hx1);

            float* od_base = od_out + ((long)i * A_ + j) * K_;
            k_odhead<<<B_, 256, 0, stream>>>(hx1, odc_W1, odc_b1, odc_W2, odc_b2,
                                             od_base, (long)E_ * A_ * K_,
                                             prev, i, pcb, pn, pred);
        }
        k_final_update<<<B_, 256, 0, stream>>>(prev, i, pred);
    }
}

// Round 4
// 2516.997 us; speedup vs baseline: 3.0880x; 1.4180x over previous
//
#include <hip/hip_runtime.h>
#include <math.h>

// Problem constants
constexpr int B_  = 64;
constexpr int S_  = 512;
constexpr int H_  = 768;
constexpr int H2_ = 1536;   // 2H
constexpr int G3_ = 2304;   // 3H
constexpr int OP_ = 18;
constexpr int C_  = 24;
constexpr int M_  = 16;
constexpr int E_  = 8;
constexpr int A_  = 3;
constexpr int K_  = 48;     // C+M+E
constexpr int HH_ = 384;    // H/2

// ---------------------------------------------------------------------------
// GEMM core: ONE WAVE (64 threads) computes 64 rows x 64 cols of C = A @ W^T
// (partial over a K-range), writing raw partials to Pout[r*ldP + c].
// - Acts AND weights staged transposed in LDS ([k][row/col], stride 68).
//   Weights read once from L2 per block (no redundancy).
// - micro-tile: 8 rows x 8 cols per thread -> 64 FMA per 4 LDS b128 reads.
// ---------------------------------------------------------------------------
__device__ __forceinline__ void gemm_core64w(
    const float* const* rowsrc,          // [64] act row pointers (null -> 0)
    const float* __restrict__ W, int wld,
    int col0g,                           // global col of this block's col 0
    int k0base, int nkt,                 // K range [k0base, k0base+nkt*32)
    float* __restrict__ Pout, int ldP)
{
    __shared__ float As[32][68];
    __shared__ float Ws[32][68];
    const int tid = threadIdx.x;         // 0..63
    const int cg = tid & 7, rg = tid >> 3;
    const int c0 = cg * 8, r0 = rg * 8;

    float acc[8][8];
    #pragma unroll
    for (int a = 0; a < 8; ++a)
        #pragma unroll
        for (int b = 0; b < 8; ++b) acc[a][b] = 0.f;

    for (int kt = 0; kt < nkt; ++kt) {
        const int k0 = k0base + kt * 32;
        __syncthreads();
        // stage 64x32 acts + 64x32 weights, both transposed
        #pragma unroll
        for (int it = 0; it < 8; ++it) {
            int f = tid + it * 64;           // 512 float4 slots
            int row = f >> 3, f4 = f & 7;
            const float* src = rowsrc[row];
            float4 v = make_float4(0.f, 0.f, 0.f, 0.f);
            if (src) v = *(const float4*)(src + k0 + f4 * 4);
            As[f4 * 4 + 0][row] = v.x;
            As[f4 * 4 + 1][row] = v.y;
            As[f4 * 4 + 2][row] = v.z;
            As[f4 * 4 + 3][row] = v.w;
            float4 w = *(const float4*)(W + (long)(col0g + row) * wld + k0 + f4 * 4);
            Ws[f4 * 4 + 0][row] = w.x;
            Ws[f4 * 4 + 1][row] = w.y;
            Ws[f4 * 4 + 2][row] = w.z;
            Ws[f4 * 4 + 3][row] = w.w;
        }
        __syncthreads();

        #pragma unroll 4
        for (int kk = 0; kk < 32; ++kk) {
            float4 a0 = *(const float4*)&As[kk][r0];
            float4 a1 = *(const float4*)&As[kk][r0 + 4];
            float4 w0 = *(const float4*)&Ws[kk][c0];
            float4 w1 = *(const float4*)&Ws[kk][c0 + 4];
            float av[8] = {a0.x, a0.y, a0.z, a0.w, a1.x, a1.y, a1.z, a1.w};
            float wv[8] = {w0.x, w0.y, w0.z, w0.w, w1.x, w1.y, w1.z, w1.w};
            #pragma unroll
            for (int rr = 0; rr < 8; ++rr)
                #pragma unroll
                for (int cc = 0; cc < 8; ++cc)
                    acc[rr][cc] += av[rr] * wv[cc];
        }
    }

    #pragma unroll
    for (int rr = 0; rr < 8; ++rr) {
        float* dst = Pout + (long)(r0 + rr) * ldP + c0;
        *(float4*)dst       = make_float4(acc[rr][0], acc[rr][1], acc[rr][2], acc[rr][3]);
        *(float4*)(dst + 4) = make_float4(acc[rr][4], acc[rr][5], acc[rr][6], acc[rr][7]);
    }
}

// ---------------------------------------------------------------------------
// GRU dual GEMM: grid (72, 8). bx<36 -> gi cols (x @ Wih^T), else gh cols.
// K=768 split 8 ways (96 each). Optional _pick row-gather on the x side.
// ---------------------------------------------------------------------------
__global__ __launch_bounds__(64) void k_gru_gemm8(
    const float* __restrict__ x, long ldx, int pickmode,
    const int* __restrict__ gopd, int i, int jm1,
    const float* __restrict__ pcb, const float* __restrict__ pnb,
    const float* __restrict__ prevb,
    const float* __restrict__ h, long ldh,
    const float* __restrict__ Wih, const float* __restrict__ Whh,
    float* __restrict__ P)
{
    __shared__ const float* rowsrc[64];
    const int bx = blockIdx.x;
    const int kz = blockIdx.y;
    const bool hside = bx >= 36;
    const int n0 = (bx % 36) * 64;

    {
        int r = threadIdx.x;
        const float* s;
        if (hside) s = h + (long)r * ldh;
        else if (!pickmode) s = x + (long)r * ldx;
        else {
            int idx = gopd[(r * E_ + i) * A_ + jm1];
            if (idx < C_)            s = pcb + (long)idx * H_;
            else if (idx < C_ + M_)  s = pnb + ((long)r * M_ + (idx - C_)) * H_;
            else                     s = prevb + ((long)r * E_ + (idx - C_ - M_)) * H_;
        }
        rowsrc[r] = s;
    }
    const float* W = hside ? Whh : Wih;
    float* Pout = P + (long)kz * 64 * 4608 + (hside ? 2304 : 0) + n0;
    gemm_core64w(rowsrc, W, 768, n0, kz * 96, 3, Pout, 4608);
}

// Sum 8 K-partials, add biases, apply GRU gates: hnew = (1-z)*n + z*h
__global__ void k_gru_finish8(const float* __restrict__ P,
                              const float* __restrict__ h, long ldh,
                              const float* __restrict__ bih, const float* __restrict__ bhh,
                              float* __restrict__ hnew)
{
    int t = blockIdx.x * 256 + threadIdx.x;       // 64*768
    int b = t / 768, c = t - b * 768;
    const float* Pb = P + (long)b * 4608;
    float ir = bih[c], iz = bih[768 + c], in_ = bih[1536 + c];
    float hr = bhh[c], hz = bhh[768 + c], hn  = bhh[1536 + c];
    #pragma unroll
    for (int z = 0; z < 8; ++z) {
        const float* q = Pb + (long)z * 64 * 4608;
        ir += q[c];        iz += q[768 + c];  in_ += q[1536 + c];
        hr += q[2304 + c]; hz += q[3072 + c]; hn  += q[3840 + c];
    }
    float r  = 1.f / (1.f + expf(-(ir + hr)));
    float z_ = 1.f / (1.f + expf(-(iz + hz)));
    float n  = tanhf(in_ + r * hn);
    float hp = h[(long)b * ldh + c];
    hnew[t] = (1.f - z_) * n + z_ * hp;
}

// ---------------------------------------------------------------------------
// Generic projection GEMM (partials): grid (ncolblk64, nrowblk, KS=4)
// ---------------------------------------------------------------------------
__global__ __launch_bounds__(64) void k_proj_gemm(
    const float* __restrict__ A, long lda, const int* __restrict__ gidx, int Mm,
    const float* __restrict__ W, int wld, int nkt,
    float* __restrict__ P, int ldP, int Mpad)
{
    __shared__ const float* rowsrc[64];
    const int n0 = blockIdx.x * 64;
    const int rb = blockIdx.y * 64;
    const int kz = blockIdx.z;
    {
        int r = rb + threadIdx.x;
        const float* s = nullptr;
        if (r < Mm) s = gidx ? (A + (long)gidx[r] * lda) : (A + (long)r * lda);
        rowsrc[threadIdx.x] = s;
    }
    float* Pout = P + ((long)kz * Mpad + rb) * ldP + n0;
    gemm_core64w(rowsrc, W, wld, n0, kz * nkt * 32, nkt, Pout, ldP);
}

// Sum KS=4 partials + bias, then LayerNorm the 768-wide row.
__global__ void k_ln_finish(const float* __restrict__ P, int ldP, int Mpad,
                            const float* __restrict__ bias, const float* __restrict__ g,
                            const float* __restrict__ be,
                            float* __restrict__ out, long ldout)
{
    int row = blockIdx.x, tid = threadIdx.x;
    __shared__ float red[256];
    float v[3];
    #pragma unroll
    for (int it = 0; it < 3; ++it) {
        int c2 = tid + it * 256;
        float s = bias[c2];
        #pragma unroll
        for (int z = 0; z < 4; ++z) s += P[((long)z * Mpad + row) * ldP + c2];
        v[it] = s;
    }
    float s = v[0] + v[1] + v[2];
    red[tid] = s; __syncthreads();
    for (int o = 128; o > 0; o >>= 1) { if (tid < o) red[tid] += red[tid + o]; __syncthreads(); }
    float mu = red[0] / 768.f;
    __syncthreads();
    float vv = 0.f;
    #pragma unroll
    for (int it = 0; it < 3; ++it) { float d = v[it] - mu; vv += d * d; }
    red[tid] = vv; __syncthreads();
    for (int o = 128; o > 0; o >>= 1) { if (tid < o) red[tid] += red[tid + o]; __syncthreads(); }
    float inv = 1.f / sqrtf(red[0] / 768.f + 1e-5f);
    #pragma unroll
    for (int it = 0; it < 3; ++it) {
        int c2 = tid + it * 256;
        out[(long)row * ldout + c2] = (v[it] - mu) * inv * g[c2] + be[c2];
    }
}

// Fused op head: hid = relu(cv@W1^T+b1) (384), logits = hid@W2^T+b2 (18)
__global__ __launch_bounds__(256) void k_ophead_fused(
    const float* __restrict__ cv,
    const float* __restrict__ W1, const float* __restrict__ b1,
    const float* __restrict__ W2, const float* __restrict__ b2,
    float* __restrict__ op_out, int i)
{
    int b = blockIdx.x, tid = threadIdx.x;
    __shared__ float xs[768];
    __shared__ float hs[384];
    const float* xr = cv + (long)b * 768;
    #pragma unroll
    for (int it = 0; it < 3; ++it) xs[tid + it * 256] = xr[tid + it * 256];
    __syncthreads();

    for (int c = tid; c < 384; c += 256) {
        const float* wr = W1 + (long)c * 768;
        float acc = 0.f;
        #pragma unroll 8
        for (int k = 0; k < 768; k += 4) {
            float4 xv = *(const float4*)&xs[k];
            float4 wv = *(const float4*)(wr + k);
            acc += xv.x * wv.x + xv.y * wv.y + xv.z * wv.z + xv.w * wv.w;
        }
        hs[c] = fmaxf(acc + b1[c], 0.f);
    }
    __syncthreads();

    int c = tid >> 3, g = tid & 7;
    float acc = 0.f;
    if (c < OP_) {
        const float* wr = W2 + (long)c * HH_;
        #pragma unroll
        for (int t = 0; t < 12; ++t) {
            int k = (g + 8 * t) * 4;
            float4 xv = *(const float4*)&hs[k];
            float4 wv = *(const float4*)(wr + k);
            acc += xv.x * wv.x + xv.y * wv.y + xv.z * wv.z + xv.w * wv.w;
        }
    }
    acc += __shfl_xor(acc, 1);
    acc += __shfl_xor(acc, 2);
    acc += __shfl_xor(acc, 4);
    if (c < OP_ && g == 0)
        op_out[((long)b * E_ + i) * OP_ + c] = acc + b2[c];
}

// ---------------------------------------------------------------------------
// Fused od head: MLP1(relu) + MLP2 + logit write + argmax + prev update + pred
// ---------------------------------------------------------------------------
__global__ __launch_bounds__(256) void k_odhead(
    const float* __restrict__ hx1,
    const float* __restrict__ W1, const float* __restrict__ b1,
    const float* __restrict__ W2, const float* __restrict__ b2,
    float* __restrict__ od_base, long ldl,
    float* __restrict__ prev, int i,
    const float* __restrict__ pcb, const float* __restrict__ pnb,
    float* __restrict__ pred)
{
    int b = blockIdx.x, tid = threadIdx.x;
    __shared__ float xs[768];
    __shared__ float hidL[24];
    __shared__ float lg[48];
    __shared__ float red[256];
    __shared__ int s_oidx;

    const float* xr = hx1 + (long)b * 768;
    #pragma unroll
    for (int it = 0; it < 3; ++it) xs[tid + it * 256] = xr[tid + it * 256];
    __syncthreads();

    int c = tid >> 3, g = tid & 7;
    float acc = 0.f;
    if (c < 24) {
        const float* wr = W1 + (long)c * 768;
        #pragma unroll
        for (int t = 0; t < 24; ++t) {
            int k = (g + 8 * t) * 4;
            float4 xv = *(const float4*)&xs[k];
            float4 wv = *(const float4*)(wr + k);
            acc += xv.x * wv.x + xv.y * wv.y + xv.z * wv.z + xv.w * wv.w;
        }
    }
    acc += __shfl_xor(acc, 1);
    acc += __shfl_xor(acc, 2);
    acc += __shfl_xor(acc, 4);
    if (c < 24 && g == 0) hidL[c] = fmaxf(acc + b1[c], 0.f);
    __syncthreads();

    if (tid < 48) {
        float a2 = b2[tid];
        const float* w2 = W2 + tid * 24;
        #pragma unroll
        for (int k = 0; k < 24; ++k) a2 += hidL[k] * w2[k];
        lg[tid] = a2;
        od_base[(long)b * ldl + tid] = a2;
    }

    float* prow = prev + ((long)b * E_ + i) * 768;
    float m = -3.4e38f;
    #pragma unroll
    for (int it = 0; it < 3; ++it) m = fmaxf(m, prow[tid + it * 256]);
    red[tid] = m; __syncthreads();
    for (int o = 128; o > 0; o >>= 1) { if (tid < o) red[tid] = fmaxf(red[tid], red[tid + o]); __syncthreads(); }

    if (tid == 0) {
        float best = lg[0]; int bi = 0;
        for (int k2 = 1; k2 < K_; ++k2) { float v = lg[k2]; if (v > best) { best = v; bi = k2; } }
        s_oidx = bi;
    }
    __syncthreads();
    int oidx = s_oidx;
    bool empty = (red[0] == 0.0f);
    if (oidx == 0 && empty) {
        #pragma unroll
        for (int it = 0; it < 3; ++it) prow[tid + it * 256] = xs[tid + it * 256];
    }
    __syncthreads();

    const float* src;
    if (oidx < C_)            src = pcb + (long)oidx * 768;
    else if (oidx < C_ + M_)  src = pnb + ((long)b * M_ + (oidx - C_)) * 768;
    else                      src = prev + ((long)b * E_ + (oidx - C_ - M_)) * 768;
    #pragma unroll
    for (int it = 0; it < 3; ++it) pred[(long)b * 768 + tid + it * 256] = src[tid + it * 256];
}

__global__ void k_final_update(float* __restrict__ prev, int i, const float* __restrict__ pred)
{
    int b = blockIdx.x, tid = threadIdx.x;
    __shared__ float red[256];
    float* prow = prev + ((long)b * E_ + i) * H_;
    float m = -3.4e38f;
    #pragma unroll
    for (int it = 0; it < 3; ++it) m = fmaxf(m, prow[tid + it * 256]);
    red[tid] = m; __syncthreads();
    for (int o = 128; o > 0; o >>= 1) { if (tid < o) red[tid] = fmaxf(red[tid], red[tid + o]); __syncthreads(); }
    if (red[0] == 0.0f) {
        #pragma unroll
        for (int it = 0; it < 3; ++it) prow[tid + it * 256] = pred[(long)b * H_ + tid + it * 256];
    }
}

// Build num_vec: for (b,m) find first/last position with number_mask==m+1
__global__ void k_numvec(const float* __restrict__ inp, const int* __restrict__ nmask,
                         float* __restrict__ numvec)
{
    int b = blockIdx.x / M_, m = blockIdx.x % M_;
    int tid = threadIdx.x;
    int fmin = S_, lmax = -1;
    for (int s = tid; s < S_; s += 256) {
        if (nmask[b * S_ + s] == m + 1) {
            if (s < fmin) fmin = s;
            if (s > lmax) lmax = s;
        }
    }
    __shared__ int sf[256], sl[256];
    sf[tid] = fmin; sl[tid] = lmax; __syncthreads();
    for (int o = 128; o > 0; o >>= 1) {
        if (tid < o) {
            sf[tid] = min(sf[tid], sf[tid + o]);
            sl[tid] = max(sl[tid], sl[tid + o]);
        }
        __syncthreads();
    }
    int first = sf[0], last = sl[0];
    bool exists = (last >= 0);
    if (!exists) { first = 0; last = 0; }
    const float* fv = inp + ((long)b * S_ + first) * H_;
    const float* lv = inp + ((long)b * S_ + last) * H_;
    float* dst = numvec + ((long)b * M_ + m) * H2_;
    for (int h = tid; h < H_; h += 256) {
        dst[h]      = exists ? fv[h] : 0.f;
        dst[H_ + h] = exists ? lv[h] : 0.f;
    }
}

__global__ void k_copy_cv(const float* __restrict__ inp, float* __restrict__ cvv)
{
    int b = blockIdx.x;
    for (int h = threadIdx.x; h < H_; h += 256)
        cvv[b * H_ + h] = inp[(long)b * S_ * H_ + h];
}

// ---------------------------------------------------------------------------
extern "C" void kernel_launch(void* const* d_in, const int* in_sizes, int n_in,
                              void* d_out, int out_size, void* d_ws, size_t ws_size,
                              hipStream_t stream)
{
    const float* inp    = (const float*)d_in[0];
    const int*   nmask  = (const int*)  d_in[3];
    const int*   gops   = (const int*)  d_in[4];
    const int*   gopd   = (const int*)  d_in[5];
    const float* constv = (const float*)d_in[6];
    const float* opv    = (const float*)d_in[7];
    const float* opj_W  = (const float*)d_in[8];
    const float* opj_b  = (const float*)d_in[9];
    const float* opj_g  = (const float*)d_in[10];
    const float* opj_be = (const float*)d_in[11];
    const float* odj_W  = (const float*)d_in[12];
    const float* odj_b  = (const float*)d_in[13];
    const float* odj_g  = (const float*)d_in[14];
    const float* odj_be = (const float*)d_in[15];
    const float* opc_W1 = (const float*)d_in[16];
    const float* opc_b1 = (const float*)d_in[17];
    const float* opc_W2 = (const float*)d_in[18];
    const float* opc_b2 = (const float*)d_in[19];
    const float* odc_W1 = (const float*)d_in[20];
    const float* odc_b1 = (const float*)d_in[21];
    const float* odc_W2 = (const float*)d_in[22];
    const float* odc_b2 = (const float*)d_in[23];
    const float* og_Wih = (const float*)d_in[24];
    const float* og_Whh = (const float*)d_in[25];
    const float* og_bih = (const float*)d_in[26];
    const float* og_bhh = (const float*)d_in[27];
    const float* cg_Wih = (const float*)d_in[28];
    const float* cg_Whh = (const float*)d_in[29];
    const float* cg_bih = (const float*)d_in[30];
    const float* cg_bhh = (const float*)d_in[31];

    float* op_out = (float*)d_out;                  // (B, E, OP)
    float* od_out = op_out + (long)B_ * E_ * OP_;   // (B, E, A, K)

    // workspace partition (floats)
    float* ws      = (float*)d_ws;
    float* num_vec = ws; ws += (long)B_ * M_ * H2_;       // 1.57M
    float* P       = ws; ws += (long)4 * 1024 * 768;      // 3.15M partials
    float* pn      = ws; ws += (long)B_ * M_ * H_;
    float* pcb     = ws; ws += (long)C_ * H_;
    float* gopv    = ws; ws += (long)B_ * E_ * H_;
    float* prev    = ws; ws += (long)B_ * E_ * H_;
    float* cv      = ws; ws += (long)B_ * H_;
    float* h0      = ws; ws += (long)B_ * H_;
    float* hx0     = ws; ws += (long)B_ * H_;
    float* hx1     = ws; ws += (long)B_ * H_;
    float* pred    = ws; ws += (long)B_ * H_;

    hipMemsetAsync(prev, 0, (size_t)B_ * E_ * H_ * sizeof(float), stream);

    // ---- preprocessing ----
    k_numvec<<<B_ * M_, 256, 0, stream>>>(inp, nmask, num_vec);

    // pn = LN(num_vec @ odj_W^T + odj_b)   M=1024, N=768, K=1536, KS=4
    k_proj_gemm<<<dim3(12, 16, 4), 64, 0, stream>>>(num_vec, H2_, nullptr, 1024,
                                                    odj_W, H2_, 12, P, H_, 1024);
    k_ln_finish<<<1024, 256, 0, stream>>>(P, H_, 1024, odj_b, odj_g, odj_be, pn, H_);

    // pc = LN(const_vector @ odj_W^T + odj_b)   M=24 (padded to 64)
    k_proj_gemm<<<dim3(12, 1, 4), 64, 0, stream>>>(constv, H2_, nullptr, C_,
                                                   odj_W, H2_, 12, P, H_, 64);
    k_ln_finish<<<C_, 256, 0, stream>>>(P, H_, 64, odj_b, odj_g, odj_be, pcb, H_);

    // gold_opv = LN(operator_vector[gold_operators] @ opj_W^T + opj_b)  M=512
    k_proj_gemm<<<dim3(12, 8, 4), 64, 0, stream>>>(opv, H2_, gops, 512,
                                                   opj_W, H2_, 12, P, H_, 512);
    k_ln_finish<<<512, 256, 0, stream>>>(P, H_, 512, opj_b, opj_g, opj_be, gopv, H_);

    k_copy_cv<<<B_, 256, 0, stream>>>(inp, cv);

    // ---- decode loop ----
    const dim3 gg(72, 8);       // GRU GEMM: 576 one-wave blocks
    const long ldE = (long)E_ * H_;

    for (int i = 0; i < E_; ++i) {
        if (i > 0) {
            const float* hrow = prev + (long)(i - 1) * H_;   // row stride E*H
            k_gru_gemm8<<<gg, 64, 0, stream>>>(cv, H_, 0, nullptr, 0, 0, nullptr, nullptr, nullptr,
                                               hrow, ldE, cg_Wih, cg_Whh, P);
            k_gru_finish8<<<192, 256, 0, stream>>>(P, hrow, ldE, cg_bih, cg_bhh, h0);
            k_gru_gemm8<<<gg, 64, 0, stream>>>(h0, H_, 0, nullptr, 0, 0, nullptr, nullptr, nullptr,
                                               hrow, ldE, cg_Wih + (long)G3_ * H_,
                                               cg_Whh + (long)G3_ * H_, P);
            k_gru_finish8<<<192, 256, 0, stream>>>(P, hrow, ldE, cg_bih + G3_, cg_bhh + G3_, cv);
        }
        // op head (fully fused)
        k_ophead_fused<<<B_, 256, 0, stream>>>(cv, opc_W1, opc_b1, opc_W2, opc_b2, op_out, i);

        for (int j = 0; j < A_; ++j) {
            const float* xptr; long ldx; int pickm;
            if (j == 0) { xptr = gopv + (long)i * H_; ldx = ldE; pickm = 0; }
            else        { xptr = nullptr; ldx = 0; pickm = 1; }
            const float* hp0 = (j == 0) ? cv : hx0;
            const float* hp1 = (j == 0) ? cv : hx1;

            k_gru_gemm8<<<gg, 64, 0, stream>>>(xptr, ldx, pickm, gopd, i, j - 1,
                                               pcb, pn, prev, hp0, H_,
                                               og_Wih, og_Whh, P);
            k_gru_finish8<<<192, 256, 0, stream>>>(P, hp0, H_, og_bih, og_bhh, hx0);
            k_gru_gemm8<<<gg, 64, 0, stream>>>(hx0, H_, 0, nullptr, 0, 0, nullptr, nullptr, nullptr,
                                               hp1, H_, og_Wih + (long)G3_ * H_,
                                               og_Whh + (long)G3_ * H_, P);
            k_gru_finish8<<<192, 256, 0, stream>>>(P, hp1, H_, og_bih + G3_, og_bhh + G3_, hx1);

            float* od_base = od_out + ((long)i * A_ + j) * K_;
            k_odhead<<<B_, 256, 0, stream>>>(hx1, odc_W1, odc_b1, odc_W2, odc_b2,
                                             od_base, (long)E_ * A_ * K_,
                                             prev, i, pcb, pn, pred);
        }
        k_final_update<<<B_, 256, 0, stream>>>(prev, i, pred);
    }
}

// Round 5
// 2331.069 us; speedup vs baseline: 3.3343x; 1.0798x over previous
//
#include <hip/hip_runtime.h>
#include <math.h>

// Problem constants
constexpr int B_  = 64;
constexpr int S_  = 512;
constexpr int H_  = 768;
constexpr int H2_ = 1536;   // 2H
constexpr int G3_ = 2304;   // 3H
constexpr int OP_ = 18;
constexpr int C_  = 24;
constexpr int M_  = 16;
constexpr int E_  = 8;
constexpr int A_  = 3;
constexpr int K_  = 48;     // C+M+E
constexpr int HH_ = 384;    // H/2

// ---------------------------------------------------------------------------
// GEMM core: ONE WAVE computes 64 rows x 64 cols of C = A @ W^T (partial over
// a K-range of nkt*32), writing raw partials to Pout[r*ldP + c].
// - Thread t stages act row t and weight row t (col0g+t) -> LDS transposed.
//   ds_write As[k][tid]: bank=(4k+tid)%32 -> 2 lanes/bank, conflict-free.
// - Register prefetch: tile kt+1's global loads issue before tile kt's
//   compute; the vmcnt wait lands after compute -> latency hidden.
// - micro-tile 8x8: 64 FMA per 4 broadcast LDS b128 reads.
// ---------------------------------------------------------------------------
__device__ __forceinline__ void gemm_core_w(
    const float* __restrict__ asrc,     // act row (= row tid), null -> zeros
    const float* __restrict__ wsrc,     // weight row (= col tid)
    int k0base, int nkt,
    float* __restrict__ Pout, int ldP)
{
    __shared__ float As[32][68];
    __shared__ float Ws[32][68];
    const int tid = threadIdx.x;         // 0..63
    const int cg = tid & 7, rg = tid >> 3;
    const int c0 = cg * 8, r0 = rg * 8;

    float acc[8][8];
    #pragma unroll
    for (int a = 0; a < 8; ++a)
        #pragma unroll
        for (int b = 0; b < 8; ++b) acc[a][b] = 0.f;

    float4 ra[8], rw[8], ra2[8], rw2[8];
    const float4 z4 = make_float4(0.f, 0.f, 0.f, 0.f);

    #pragma unroll
    for (int c = 0; c < 8; ++c) {
        ra[c] = asrc ? *(const float4*)(asrc + k0base + c * 4) : z4;
        rw[c] = *(const float4*)(wsrc + k0base + c * 4);
    }

    for (int kt = 0; kt < nkt; ++kt) {
        __syncthreads();
        #pragma unroll
        for (int c = 0; c < 8; ++c) {
            As[c * 4 + 0][tid] = ra[c].x; As[c * 4 + 1][tid] = ra[c].y;
            As[c * 4 + 2][tid] = ra[c].z; As[c * 4 + 3][tid] = ra[c].w;
            Ws[c * 4 + 0][tid] = rw[c].x; Ws[c * 4 + 1][tid] = rw[c].y;
            Ws[c * 4 + 2][tid] = rw[c].z; Ws[c * 4 + 3][tid] = rw[c].w;
        }
        if (kt + 1 < nkt) {
            const int k0 = k0base + (kt + 1) * 32;
            #pragma unroll
            for (int c = 0; c < 8; ++c) {
                ra2[c] = asrc ? *(const float4*)(asrc + k0 + c * 4) : z4;
                rw2[c] = *(const float4*)(wsrc + k0 + c * 4);
            }
        }
        __syncthreads();

        #pragma unroll 4
        for (int kk = 0; kk < 32; ++kk) {
            float4 a0 = *(const float4*)&As[kk][r0];
            float4 a1 = *(const float4*)&As[kk][r0 + 4];
            float4 w0 = *(const float4*)&Ws[kk][c0];
            float4 w1 = *(const float4*)&Ws[kk][c0 + 4];
            float av[8] = {a0.x, a0.y, a0.z, a0.w, a1.x, a1.y, a1.z, a1.w};
            float wv[8] = {w0.x, w0.y, w0.z, w0.w, w1.x, w1.y, w1.z, w1.w};
            #pragma unroll
            for (int rr = 0; rr < 8; ++rr)
                #pragma unroll
                for (int cc = 0; cc < 8; ++cc)
                    acc[rr][cc] += av[rr] * wv[cc];
        }
        #pragma unroll
        for (int c = 0; c < 8; ++c) { ra[c] = ra2[c]; rw[c] = rw2[c]; }
    }

    #pragma unroll
    for (int rr = 0; rr < 8; ++rr) {
        float* dst = Pout + (long)(r0 + rr) * ldP + c0;
        *(float4*)dst       = make_float4(acc[rr][0], acc[rr][1], acc[rr][2], acc[rr][3]);
        *(float4*)(dst + 4) = make_float4(acc[rr][4], acc[rr][5], acc[rr][6], acc[rr][7]);
    }
}

// ---------------------------------------------------------------------------
// GRU dual GEMM: grid (72, 12). bx<36 -> gi cols (x @ Wih^T), else gh cols.
// K=768 split 12 ways (64 each, nkt=2). Optional _pick row-gather on x side.
// ---------------------------------------------------------------------------
__global__ __launch_bounds__(64) void k_gru_gemm12(
    const float* __restrict__ x, long ldx, int pickmode,
    const int* __restrict__ gopd, int i, int jm1,
    const float* __restrict__ pcb, const float* __restrict__ pnb,
    const float* __restrict__ prevb,
    const float* __restrict__ h, long ldh,
    const float* __restrict__ Wih, const float* __restrict__ Whh,
    float* __restrict__ P)
{
    const int tid = threadIdx.x;
    const int bx = blockIdx.x;
    const int kz = blockIdx.y;
    const bool hside = bx >= 36;
    const int n0 = (bx % 36) * 64;

    const float* s;
    if (hside) s = h + (long)tid * ldh;
    else if (!pickmode) s = x + (long)tid * ldx;
    else {
        int idx = gopd[(tid * E_ + i) * A_ + jm1];
        if (idx < C_)            s = pcb + (long)idx * H_;
        else if (idx < C_ + M_)  s = pnb + ((long)tid * M_ + (idx - C_)) * H_;
        else                     s = prevb + ((long)tid * E_ + (idx - C_ - M_)) * H_;
    }
    const float* wsrc = (hside ? Whh : Wih) + (long)(n0 + tid) * 768;
    float* Pout = P + (long)kz * 64 * 4608 + (hside ? 2304 : 0) + n0;
    gemm_core_w(s, wsrc, kz * 64, 2, Pout, 4608);
}

// Sum 12 K-partials, add biases, apply GRU gates: hnew = (1-z)*n + z*h
__global__ void k_gru_finish12(const float* __restrict__ P,
                               const float* __restrict__ h, long ldh,
                               const float* __restrict__ bih, const float* __restrict__ bhh,
                               float* __restrict__ hnew)
{
    int t = blockIdx.x * 256 + threadIdx.x;       // 64*768
    int b = t / 768, c = t - b * 768;
    const float* Pb = P + (long)b * 4608;
    float ir = bih[c], iz = bih[768 + c], in_ = bih[1536 + c];
    float hr = bhh[c], hz = bhh[768 + c], hn  = bhh[1536 + c];
    #pragma unroll
    for (int z = 0; z < 12; ++z) {
        const float* q = Pb + (long)z * 64 * 4608;
        ir += q[c];        iz += q[768 + c];  in_ += q[1536 + c];
        hr += q[2304 + c]; hz += q[3072 + c]; hn  += q[3840 + c];
    }
    float r  = 1.f / (1.f + expf(-(ir + hr)));
    float z_ = 1.f / (1.f + expf(-(iz + hz)));
    float n  = tanhf(in_ + r * hn);
    float hp = h[(long)b * ldh + c];
    hnew[t] = (1.f - z_) * n + z_ * hp;
}

// ---------------------------------------------------------------------------
// Generic projection GEMM (partials): grid (ncolblk64, nrowblk, KS=6)
// ---------------------------------------------------------------------------
__global__ __launch_bounds__(64) void k_proj_gemm(
    const float* __restrict__ A, long lda, const int* __restrict__ gidx, int Mm,
    const float* __restrict__ W, int wld, int nkt,
    float* __restrict__ P, int ldP, int Mpad)
{
    const int tid = threadIdx.x;
    const int n0 = blockIdx.x * 64;
    const int rb = blockIdx.y * 64;
    const int kz = blockIdx.z;
    int r = rb + tid;
    const float* asrc = nullptr;
    if (r < Mm) asrc = gidx ? (A + (long)gidx[r] * lda) : (A + (long)r * lda);
    const float* wsrc = W + (long)(n0 + tid) * wld;
    float* Pout = P + ((long)kz * Mpad + rb) * ldP + n0;
    gemm_core_w(asrc, wsrc, kz * nkt * 32, nkt, Pout, ldP);
}

// Sum KS partials + bias, then LayerNorm the 768-wide row.
__global__ void k_ln_finish(const float* __restrict__ P, int ldP, int Mpad, int KS,
                            const float* __restrict__ bias, const float* __restrict__ g,
                            const float* __restrict__ be,
                            float* __restrict__ out, long ldout)
{
    int row = blockIdx.x, tid = threadIdx.x;
    __shared__ float red[256];
    float v[3];
    #pragma unroll
    for (int it = 0; it < 3; ++it) {
        int c2 = tid + it * 256;
        float s = bias[c2];
        for (int z = 0; z < KS; ++z) s += P[((long)z * Mpad + row) * ldP + c2];
        v[it] = s;
    }
    float s = v[0] + v[1] + v[2];
    red[tid] = s; __syncthreads();
    for (int o = 128; o > 0; o >>= 1) { if (tid < o) red[tid] += red[tid + o]; __syncthreads(); }
    float mu = red[0] / 768.f;
    __syncthreads();
    float vv = 0.f;
    #pragma unroll
    for (int it = 0; it < 3; ++it) { float d = v[it] - mu; vv += d * d; }
    red[tid] = vv; __syncthreads();
    for (int o = 128; o > 0; o >>= 1) { if (tid < o) red[tid] += red[tid + o]; __syncthreads(); }
    float inv = 1.f / sqrtf(red[0] / 768.f + 1e-5f);
    #pragma unroll
    for (int it = 0; it < 3; ++it) {
        int c2 = tid + it * 256;
        out[(long)row * ldout + c2] = (v[it] - mu) * inv * g[c2] + be[c2];
    }
}

// Fused op head: hid = relu(cv@W1^T+b1) (384), logits = hid@W2^T+b2 (18)
__global__ __launch_bounds__(256) void k_ophead_fused(
    const float* __restrict__ cv,
    const float* __restrict__ W1, const float* __restrict__ b1,
    const float* __restrict__ W2, const float* __restrict__ b2,
    float* __restrict__ op_out, int i)
{
    int b = blockIdx.x, tid = threadIdx.x;
    __shared__ float xs[768];
    __shared__ float hs[384];
    const float* xr = cv + (long)b * 768;
    #pragma unroll
    for (int it = 0; it < 3; ++it) xs[tid + it * 256] = xr[tid + it * 256];
    __syncthreads();

    for (int c = tid; c < 384; c += 256) {
        const float* wr = W1 + (long)c * 768;
        float acc = 0.f;
        #pragma unroll 8
        for (int k = 0; k < 768; k += 4) {
            float4 xv = *(const float4*)&xs[k];
            float4 wv = *(const float4*)(wr + k);
            acc += xv.x * wv.x + xv.y * wv.y + xv.z * wv.z + xv.w * wv.w;
        }
        hs[c] = fmaxf(acc + b1[c], 0.f);
    }
    __syncthreads();

    int c = tid >> 3, g = tid & 7;
    float acc = 0.f;
    if (c < OP_) {
        const float* wr = W2 + (long)c * HH_;
        #pragma unroll
        for (int t = 0; t < 12; ++t) {
            int k = (g + 8 * t) * 4;
            float4 xv = *(const float4*)&hs[k];
            float4 wv = *(const float4*)(wr + k);
            acc += xv.x * wv.x + xv.y * wv.y + xv.z * wv.z + xv.w * wv.w;
        }
    }
    acc += __shfl_xor(acc, 1);
    acc += __shfl_xor(acc, 2);
    acc += __shfl_xor(acc, 4);
    if (c < OP_ && g == 0)
        op_out[((long)b * E_ + i) * OP_ + c] = acc + b2[c];
}

// ---------------------------------------------------------------------------
// Fused od head: MLP1(relu) + MLP2 + logit write + argmax + prev update + pred
// ---------------------------------------------------------------------------
__global__ __launch_bounds__(256) void k_odhead(
    const float* __restrict__ hx1,
    const float* __restrict__ W1, const float* __restrict__ b1,
    const float* __restrict__ W2, const float* __restrict__ b2,
    float* __restrict__ od_base, long ldl,
    float* __restrict__ prev, int i,
    const float* __restrict__ pcb, const float* __restrict__ pnb,
    float* __restrict__ pred)
{
    int b = blockIdx.x, tid = threadIdx.x;
    __shared__ float xs[768];
    __shared__ float hidL[24];
    __shared__ float lg[48];
    __shared__ float red[256];
    __shared__ int s_oidx;

    const float* xr = hx1 + (long)b * 768;
    #pragma unroll
    for (int it = 0; it < 3; ++it) xs[tid + it * 256] = xr[tid + it * 256];
    __syncthreads();

    int c = tid >> 3, g = tid & 7;
    float acc = 0.f;
    if (c < 24) {
        const float* wr = W1 + (long)c * 768;
        #pragma unroll
        for (int t = 0; t < 24; ++t) {
            int k = (g + 8 * t) * 4;
            float4 xv = *(const float4*)&xs[k];
            float4 wv = *(const float4*)(wr + k);
            acc += xv.x * wv.x + xv.y * wv.y + xv.z * wv.z + xv.w * wv.w;
        }
    }
    acc += __shfl_xor(acc, 1);
    acc += __shfl_xor(acc, 2);
    acc += __shfl_xor(acc, 4);
    if (c < 24 && g == 0) hidL[c] = fmaxf(acc + b1[c], 0.f);
    __syncthreads();

    if (tid < 48) {
        float a2 = b2[tid];
        const float* w2 = W2 + tid * 24;
        #pragma unroll
        for (int k = 0; k < 24; ++k) a2 += hidL[k] * w2[k];
        lg[tid] = a2;
        od_base[(long)b * ldl + tid] = a2;
    }

    float* prow = prev + ((long)b * E_ + i) * 768;
    float m = -3.4e38f;
    #pragma unroll
    for (int it = 0; it < 3; ++it) m = fmaxf(m, prow[tid + it * 256]);
    red[tid] = m; __syncthreads();
    for (int o = 128; o > 0; o >>= 1) { if (tid < o) red[tid] = fmaxf(red[tid], red[tid + o]); __syncthreads(); }

    if (tid == 0) {
        float best = lg[0]; int bi = 0;
        for (int k2 = 1; k2 < K_; ++k2) { float v = lg[k2]; if (v > best) { best = v; bi = k2; } }
        s_oidx = bi;
    }
    __syncthreads();
    int oidx = s_oidx;
    bool empty = (red[0] == 0.0f);
    if (oidx == 0 && empty) {
        #pragma unroll
        for (int it = 0; it < 3; ++it) prow[tid + it * 256] = xs[tid + it * 256];
    }
    __syncthreads();

    const float* src;
    if (oidx < C_)            src = pcb + (long)oidx * 768;
    else if (oidx < C_ + M_)  src = pnb + ((long)b * M_ + (oidx - C_)) * 768;
    else                      src = prev + ((long)b * E_ + (oidx - C_ - M_)) * 768;
    #pragma unroll
    for (int it = 0; it < 3; ++it) pred[(long)b * 768 + tid + it * 256] = src[tid + it * 256];
}

__global__ void k_final_update(float* __restrict__ prev, int i, const float* __restrict__ pred)
{
    int b = blockIdx.x, tid = threadIdx.x;
    __shared__ float red[256];
    float* prow = prev + ((long)b * E_ + i) * H_;
    float m = -3.4e38f;
    #pragma unroll
    for (int it = 0; it < 3; ++it) m = fmaxf(m, prow[tid + it * 256]);
    red[tid] = m; __syncthreads();
    for (int o = 128; o > 0; o >>= 1) { if (tid < o) red[tid] = fmaxf(red[tid], red[tid + o]); __syncthreads(); }
    if (red[0] == 0.0f) {
        #pragma unroll
        for (int it = 0; it < 3; ++it) prow[tid + it * 256] = pred[(long)b * H_ + tid + it * 256];
    }
}

// Build num_vec: for (b,m) find first/last position with number_mask==m+1
__global__ void k_numvec(const float* __restrict__ inp, const int* __restrict__ nmask,
                         float* __restrict__ numvec)
{
    int b = blockIdx.x / M_, m = blockIdx.x % M_;
    int tid = threadIdx.x;
    int fmin = S_, lmax = -1;
    for (int s = tid; s < S_; s += 256) {
        if (nmask[b * S_ + s] == m + 1) {
            if (s < fmin) fmin = s;
            if (s > lmax) lmax = s;
        }
    }
    __shared__ int sf[256], sl[256];
    sf[tid] = fmin; sl[tid] = lmax; __syncthreads();
    for (int o = 128; o > 0; o >>= 1) {
        if (tid < o) {
            sf[tid] = min(sf[tid], sf[tid + o]);
            sl[tid] = max(sl[tid], sl[tid + o]);
        }
        __syncthreads();
    }
    int first = sf[0], last = sl[0];
    bool exists = (last >= 0);
    if (!exists) { first = 0; last = 0; }
    const float* fv = inp + ((long)b * S_ + first) * H_;
    const float* lv = inp + ((long)b * S_ + last) * H_;
    float* dst = numvec + ((long)b * M_ + m) * H2_;
    for (int h = tid; h < H_; h += 256) {
        dst[h]      = exists ? fv[h] : 0.f;
        dst[H_ + h] = exists ? lv[h] : 0.f;
    }
}

__global__ void k_copy_cv(const float* __restrict__ inp, float* __restrict__ cvv)
{
    int b = blockIdx.x;
    for (int h = threadIdx.x; h < H_; h += 256)
        cvv[b * H_ + h] = inp[(long)b * S_ * H_ + h];
}

// ---------------------------------------------------------------------------
extern "C" void kernel_launch(void* const* d_in, const int* in_sizes, int n_in,
                              void* d_out, int out_size, void* d_ws, size_t ws_size,
                              hipStream_t stream)
{
    const float* inp    = (const float*)d_in[0];
    const int*   nmask  = (const int*)  d_in[3];
    const int*   gops   = (const int*)  d_in[4];
    const int*   gopd   = (const int*)  d_in[5];
    const float* constv = (const float*)d_in[6];
    const float* opv    = (const float*)d_in[7];
    const float* opj_W  = (const float*)d_in[8];
    const float* opj_b  = (const float*)d_in[9];
    const float* opj_g  = (const float*)d_in[10];
    const float* opj_be = (const float*)d_in[11];
    const float* odj_W  = (const float*)d_in[12];
    const float* odj_b  = (const float*)d_in[13];
    const float* odj_g  = (const float*)d_in[14];
    const float* odj_be = (const float*)d_in[15];
    const float* opc_W1 = (const float*)d_in[16];
    const float* opc_b1 = (const float*)d_in[17];
    const float* opc_W2 = (const float*)d_in[18];
    const float* opc_b2 = (const float*)d_in[19];
    const float* odc_W1 = (const float*)d_in[20];
    const float* odc_b1 = (const float*)d_in[21];
    const float* odc_W2 = (const float*)d_in[22];
    const float* odc_b2 = (const float*)d_in[23];
    const float* og_Wih = (const float*)d_in[24];
    const float* og_Whh = (const float*)d_in[25];
    const float* og_bih = (const float*)d_in[26];
    const float* og_bhh = (const float*)d_in[27];
    const float* cg_Wih = (const float*)d_in[28];
    const float* cg_Whh = (const float*)d_in[29];
    const float* cg_bih = (const float*)d_in[30];
    const float* cg_bhh = (const float*)d_in[31];

    float* op_out = (float*)d_out;                  // (B, E, OP)
    float* od_out = op_out + (long)B_ * E_ * OP_;   // (B, E, A, K)

    // workspace partition (floats), ~32 MB total
    float* ws      = (float*)d_ws;
    float* num_vec = ws; ws += (long)B_ * M_ * H2_;       // 1.57M
    float* P       = ws; ws += (long)6 * 1024 * 768;      // 4.72M partials (shared)
    float* pn      = ws; ws += (long)B_ * M_ * H_;
    float* pcb     = ws; ws += (long)C_ * H_;
    float* gopv    = ws; ws += (long)B_ * E_ * H_;
    float* prev    = ws; ws += (long)B_ * E_ * H_;
    float* cv      = ws; ws += (long)B_ * H_;
    float* h0      = ws; ws += (long)B_ * H_;
    float* hx0     = ws; ws += (long)B_ * H_;
    float* hx1     = ws; ws += (long)B_ * H_;
    float* pred    = ws; ws += (long)B_ * H_;

    hipMemsetAsync(prev, 0, (size_t)B_ * E_ * H_ * sizeof(float), stream);

    // ---- preprocessing ----
    k_numvec<<<B_ * M_, 256, 0, stream>>>(inp, nmask, num_vec);

    // pn = LN(num_vec @ odj_W^T + odj_b)   M=1024, N=768, K=1536, KS=6 (nkt=8)
    k_proj_gemm<<<dim3(12, 16, 6), 64, 0, stream>>>(num_vec, H2_, nullptr, 1024,
                                                    odj_W, H2_, 8, P, H_, 1024);
    k_ln_finish<<<1024, 256, 0, stream>>>(P, H_, 1024, 6, odj_b, odj_g, odj_be, pn, H_);

    // pc = LN(const_vector @ odj_W^T + odj_b)   M=24 (padded to 64)
    k_proj_gemm<<<dim3(12, 1, 6), 64, 0, stream>>>(constv, H2_, nullptr, C_,
                                                   odj_W, H2_, 8, P, H_, 64);
    k_ln_finish<<<C_, 256, 0, stream>>>(P, H_, 64, 6, odj_b, odj_g, odj_be, pcb, H_);

    // gold_opv = LN(operator_vector[gold_operators] @ opj_W^T + opj_b)  M=512
    k_proj_gemm<<<dim3(12, 8, 6), 64, 0, stream>>>(opv, H2_, gops, 512,
                                                   opj_W, H2_, 8, P, H_, 512);
    k_ln_finish<<<512, 256, 0, stream>>>(P, H_, 512, 6, opj_b, opj_g, opj_be, gopv, H_);

    k_copy_cv<<<B_, 256, 0, stream>>>(inp, cv);

    // ---- decode loop ----
    const dim3 gg(72, 12);      // GRU GEMM: 864 one-wave blocks
    const long ldE = (long)E_ * H_;

    for (int i = 0; i < E_; ++i) {
        if (i > 0) {
            const float* hrow = prev + (long)(i - 1) * H_;   // row stride E*H
            k_gru_gemm12<<<gg, 64, 0, stream>>>(cv, H_, 0, nullptr, 0, 0, nullptr, nullptr, nullptr,
                                                hrow, ldE, cg_Wih, cg_Whh, P);
            k_gru_finish12<<<192, 256, 0, stream>>>(P, hrow, ldE, cg_bih, cg_bhh, h0);
            k_gru_gemm12<<<gg, 64, 0, stream>>>(h0, H_, 0, nullptr, 0, 0, nullptr, nullptr, nullptr,
                                                hrow, ldE, cg_Wih + (long)G3_ * H_,
                                                cg_Whh + (long)G3_ * H_, P);
            k_gru_finish12<<<192, 256, 0, stream>>>(P, hrow, ldE, cg_bih + G3_, cg_bhh + G3_, cv);
        }
        // op head (fully fused)
        k_ophead_fused<<<B_, 256, 0, stream>>>(cv, opc_W1, opc_b1, opc_W2, opc_b2, op_out, i);

        for (int j = 0; j < A_; ++j) {
            const float* xptr; long ldx; int pickm;
            if (j == 0) { xptr = gopv + (long)i * H_; ldx = ldE; pickm = 0; }
            else        { xptr = nullptr; ldx = 0; pickm = 1; }
            const float* hp0 = (j == 0) ? cv : hx0;
            const float* hp1 = (j == 0) ? cv : hx1;

            k_gru_gemm12<<<gg, 64, 0, stream>>>(xptr, ldx, pickm, gopd, i, j - 1,
                                                pcb, pn, prev, hp0, H_,
                                                og_Wih, og_Whh, P);
            k_gru_finish12<<<192, 256, 0, stream>>>(P, hp0, H_, og_bih, og_bhh, hx0);
            k_gru_gemm12<<<gg, 64, 0, stream>>>(hx0, H_, 0, nullptr, 0, 0, nullptr, nullptr, nullptr,
                                                hp1, H_, og_Wih + (long)G3_ * H_,
                                                og_Whh + (long)G3_ * H_, P);
            k_gru_finish12<<<192, 256, 0, stream>>>(P, hp1, H_, og_bih + G3_, og_bhh + G3_, hx1);

            float* od_base = od_out + ((long)i * A_ + j) * K_;
            k_odhead<<<B_, 256, 0, stream>>>(hx1, odc_W1, odc_b1, odc_W2, odc_b2,
                                             od_base, (long)E_ * A_ * K_,
                                             prev, i, pcb, pn, pred);
        }
        k_final_update<<<B_, 256, 0, stream>>>(prev, i, pred);
    }
}